// Round 1
// baseline (3957.806 us; speedup 1.0000x reference)
//
#include <hip/hip_runtime.h>

using u32 = unsigned int;
using u16 = unsigned short;

#define B_   4
#define S_   2048
#define D_   512
#define H_   8
#define DH_  64
#define FF_  2048
#define L_   6
#define NB_  32
#define KC_  8

typedef __attribute__((ext_vector_type(8))) __bf16 bf16x8;
typedef __attribute__((ext_vector_type(4))) float  f32x4;

// ---------- helpers ----------
__device__ __forceinline__ u16 f2b(float f) {
  union { float f; u32 u; } x; x.f = f;
  u32 u = x.u;
  u32 r = (u + 0x7fffu + ((u >> 16) & 1u)) >> 16;
  return (u16)r;
}

__device__ __forceinline__ float gelu_f(float x) {
  return 0.5f * x * (1.0f + tanhf(0.7978845608028654f * (x + 0.044715f * x * x * x)));
}

// load 16 contiguous bf16 (as u16) -> 16 floats (×scale) into dst[0..15]
__device__ __forceinline__ void load16(const u16* __restrict__ p, float scale, float* dst) {
  const uint4* s4 = (const uint4*)p;
  uint4 u0 = s4[0];
  uint4 u1 = s4[1];
  u32 us[8] = {u0.x, u0.y, u0.z, u0.w, u1.x, u1.y, u1.z, u1.w};
#pragma unroll
  for (int i = 0; i < 8; i++) {
    union { u32 u; float f; } lo, hi;
    lo.u = us[i] << 16;
    hi.u = us[i] & 0xffff0000u;
    dst[2 * i]     = lo.f * scale;
    dst[2 * i + 1] = hi.f * scale;
  }
}

// ---------- MT19937 (numpy RandomState-exact) ----------
__device__ u32 mt_next(u32* mt, int& mti) {
  if (mti >= 624) {
    for (int k = 0; k < 624; k++) {
      u32 y = (mt[k] & 0x80000000u) | (mt[(k + 1) % 624] & 0x7fffffffu);
      mt[k] = mt[(k + 397) % 624] ^ (y >> 1) ^ ((y & 1u) ? 0x9908b0dfu : 0u);
    }
    mti = 0;
  }
  u32 y = mt[mti++];
  y ^= y >> 11;
  y ^= (y << 7)  & 0x9d2c5680u;
  y ^= (y << 15) & 0xefc60000u;
  y ^= y >> 18;
  return y;
}

__device__ u32 mt_interval(u32* mt, int& mti, u32 mx) {
  if (mx == 0u) return 0u;
  u32 mask = mx;
  mask |= mask >> 1; mask |= mask >> 2; mask |= mask >> 4;
  mask |= mask >> 8; mask |= mask >> 16;
  u32 v;
  while ((v = (mt_next(mt, mti) & mask)) > mx) {}
  return v;
}

// one thread per layer: replicate _block_plan(NB, l) exactly
__global__ __launch_bounds__(64)
void plan_kernel(int* __restrict__ idx, int* __restrict__ msk) {
  __shared__ u32 mts[L_][624];
  const int l = threadIdx.x;
  if (l >= L_) return;
  u32* mt = mts[l];
  u32 s = (u32)l;
  mt[0] = s;
  for (int i = 1; i < 624; i++)
    mt[i] = 1812433253u * (mt[i - 1] ^ (mt[i - 1] >> 30)) + (u32)i;
  int mti = 624;

  for (int i = 0; i < NB_; i++) {
    bool fixedv[NB_];
    for (int j = 0; j < NB_; j++) fixedv[j] = false;
    fixedv[0] = true; fixedv[NB_ - 1] = true;
    for (int j = i - 1; j <= i + 1; j++)
      if (j >= 0 && j < NB_) fixedv[j] = true;

    int rest[NB_]; int nr = 0;
    for (int j = 0; j < NB_; j++) if (!fixedv[j]) rest[nr++] = j;

    int perm[NB_];
    for (int t = 0; t < nr; t++) perm[t] = t;
    for (int t = nr - 1; t >= 1; t--) {
      int j = (int)mt_interval(mt, mti, (u32)t);
      int tmp = perm[t]; perm[t] = perm[j]; perm[j] = tmp;
    }

    bool sel[NB_];
    for (int j = 0; j < NB_; j++) sel[j] = fixedv[j];
    for (int c = 0; c < 3; c++) sel[rest[perm[c]]] = true;

    int cnt = 0;
    for (int j = 0; j < NB_; j++) {
      if (sel[j]) {
        idx[(l * NB_ + i) * KC_ + cnt] = j;
        msk[(l * NB_ + i) * KC_ + cnt] = 1;
        cnt++;
      }
    }
    for (; cnt < KC_; cnt++) {
      idx[(l * NB_ + i) * KC_ + cnt] = 0;
      msk[(l * NB_ + i) * KC_ + cnt] = 0;
    }
  }
}

// ---------- weight transpose-convert: in f32 [L][R][C] -> out bf16 [L][C][R] ----------
__global__ __launch_bounds__(256)
void transpose_conv(const float* __restrict__ in, u16* __restrict__ out, int R, int C) {
  __shared__ float tile[32][33];
  const int l = blockIdx.z;
  const float* src = in + (size_t)l * R * C;
  u16* dst = out + (size_t)l * R * C;
  const int c0 = blockIdx.x * 32, r0 = blockIdx.y * 32;
  const int tx = threadIdx.x, ty = threadIdx.y;
#pragma unroll
  for (int i = 0; i < 4; i++)
    tile[ty + i * 8][tx] = src[(size_t)(r0 + ty + i * 8) * C + c0 + tx];
  __syncthreads();
#pragma unroll
  for (int i = 0; i < 4; i++)
    dst[(size_t)(c0 + ty + i * 8) * R + r0 + tx] = f2b(tile[tx][ty + i * 8]);
}

// ---------- embedding + sinusoidal pos ----------
__global__ __launch_bounds__(128)
void embed_kernel(const int* __restrict__ tokens, const float* __restrict__ emb,
                  float* __restrict__ x) {
  const int row = blockIdx.x;           // b*S + s
  const int s = row & (S_ - 1);
  const int t = threadIdx.x;
  const int tok = tokens[row];
  float4 v = ((const float4*)(emb + (size_t)tok * D_))[t];
  float va[4] = {v.x, v.y, v.z, v.w};
  const float cc = -2.0f * logf(10000.0f) / (float)D_;
  const float pos = (float)s;
#pragma unroll
  for (int j = 0; j < 4; j++) {
    int d = t * 4 + j;
    int i = d >> 1;
    float dv = expf(cc * (float)i);
    float ang = pos * dv;
    va[j] += (d & 1) ? cosf(ang) : sinf(ang);
  }
  ((float4*)x)[(size_t)row * (D_ / 4) + t] = make_float4(va[0], va[1], va[2], va[3]);
}

// ---------- layernorm: f32 in -> bf16 (or f32) out ----------
template <bool BF16OUT>
__global__ __launch_bounds__(128)
void ln_kernel(const float* __restrict__ x, const float* __restrict__ sc,
               const float* __restrict__ bi, void* __restrict__ outp) {
  const int row = blockIdx.x;
  const int t = threadIdx.x;
  float4 v = ((const float4*)(x + (size_t)row * D_))[t];
  float va[4] = {v.x, v.y, v.z, v.w};
  float s = va[0] + va[1] + va[2] + va[3];
  float sq = va[0] * va[0] + va[1] * va[1] + va[2] * va[2] + va[3] * va[3];
#pragma unroll
  for (int d = 1; d < 64; d <<= 1) {
    s  += __shfl_xor(s, d);
    sq += __shfl_xor(sq, d);
  }
  __shared__ float red[4];
  const int wv = t >> 6, lane = t & 63;
  if (lane == 0) { red[wv * 2] = s; red[wv * 2 + 1] = sq; }
  __syncthreads();
  const float ts  = red[0] + red[2];
  const float tsq = red[1] + red[3];
  const float mean = ts * (1.0f / (float)D_);
  const float inv  = rsqrtf(tsq * (1.0f / (float)D_) - mean * mean + 1e-6f);
  const int d0 = t * 4;
  float o[4];
#pragma unroll
  for (int j = 0; j < 4; j++)
    o[j] = (va[j] - mean) * inv * sc[d0 + j] + bi[d0 + j];
  if (BF16OUT) {
    ushort4 u;
    u.x = f2b(o[0]); u.y = f2b(o[1]); u.z = f2b(o[2]); u.w = f2b(o[3]);
    ((ushort4*)outp)[(size_t)row * (D_ / 4) + t] = u;
  } else {
    ((float4*)outp)[(size_t)row * (D_ / 4) + t] = make_float4(o[0], o[1], o[2], o[3]);
  }
}

// ---------- bf16 MFMA GEMM:  C[M,N] = A[M,K] * BT[N,K]^T  (+ epilogue) ----------
// MODE 0: out bf16
// MODE 1: out f32 = acc + resid
// MODE 2: out bf16 = gelu(acc + bias)
// MODE 3: out f32 = acc + bias + resid
template <int MODE>
__global__ __launch_bounds__(256)
void gemm_bt(const u16* __restrict__ A, const u16* __restrict__ BT,
             int Mm, int Nn, int Kk,
             float* __restrict__ outf, u16* __restrict__ outb,
             const float* __restrict__ bias, const float* __restrict__ resid) {
  __shared__ u16 As[128 * 32];
  __shared__ u16 Bs[128 * 32];
  const int tid = threadIdx.x;
  const int wave = tid >> 6, lane = tid & 63;
  const int row0 = blockIdx.x * 128, col0 = blockIdx.y * 128;
  const int wr = wave >> 1, wc = wave & 1;
  const int l15 = lane & 15, l4 = lane >> 4;
  f32x4 acc[4][4] = {};

  for (int k0 = 0; k0 < Kk; k0 += 32) {
    __syncthreads();
#pragma unroll
    for (int i = 0; i < 2; i++) {
      int chunk = wave * 128 + i * 64 + lane;   // 0..511, 16B each
      int r = chunk >> 2, kp = (chunk & 3) << 3;
      *(uint4*)(As + chunk * 8) = *(const uint4*)(A  + (size_t)(row0 + r) * Kk + k0 + kp);
      *(uint4*)(Bs + chunk * 8) = *(const uint4*)(BT + (size_t)(col0 + r) * Kk + k0 + kp);
    }
    __syncthreads();
    bf16x8 af[4], bfr[4];
#pragma unroll
    for (int m = 0; m < 4; m++)
      af[m] = *(const bf16x8*)(As + (wr * 64 + m * 16 + l15) * 32 + l4 * 8);
#pragma unroll
    for (int n = 0; n < 4; n++)
      bfr[n] = *(const bf16x8*)(Bs + (wc * 64 + n * 16 + l15) * 32 + l4 * 8);
#pragma unroll
    for (int m = 0; m < 4; m++)
#pragma unroll
      for (int n = 0; n < 4; n++)
        acc[m][n] = __builtin_amdgcn_mfma_f32_16x16x32_bf16(af[m], bfr[n], acc[m][n], 0, 0, 0);
  }

#pragma unroll
  for (int m = 0; m < 4; m++) {
#pragma unroll
    for (int n = 0; n < 4; n++) {
#pragma unroll
      for (int j = 0; j < 4; j++) {
        const int r = row0 + wr * 64 + m * 16 + l4 * 4 + j;
        const int c = col0 + wc * 64 + n * 16 + l15;
        const size_t o = (size_t)r * Nn + c;
        float v = acc[m][n][j];
        if (MODE == 0) {
          outb[o] = f2b(v);
        } else if (MODE == 1) {
          outf[o] = v + resid[o];
        } else if (MODE == 2) {
          outb[o] = f2b(gelu_f(v + bias[c]));
        } else {
          outf[o] = v + bias[c] + resid[o];
        }
      }
    }
  }
}

// ---------- block-sparse attention (one wg per (b, block, head)) ----------
__global__ __launch_bounds__(256)
void attn_kernel(const u16* __restrict__ qb, const u16* __restrict__ kb,
                 const u16* __restrict__ vb, const int* __restrict__ tokens,
                 const int* __restrict__ pidx, const int* __restrict__ pmsk,
                 u16* __restrict__ outb) {
  __shared__ float qs[64][65];
  __shared__ float ks[64][65];
  __shared__ float ps[64][65];
  __shared__ float vs[64][68];

  const int blk = blockIdx.x;
  const int h = blk & (H_ - 1);
  const int n = (blk >> 3) & (NB_ - 1);
  const int b = blk >> 8;
  const int t = threadIdx.x;
  const int qrow = t >> 2, quarter = t & 3;
  const int e0 = quarter * 16;

  // q tile, pre-scaled by 1/sqrt(DH)
  load16(qb + ((size_t)(b * S_ + n * 64 + qrow) * D_) + h * 64 + e0, 0.125f, &qs[qrow][e0]);

  float o[16];
#pragma unroll
  for (int j = 0; j < 16; j++) o[j] = 0.0f;
  float mrow = -1e30f, ssum = 0.0f;

  for (int kc = 0; kc < KC_; kc++) {
    if (!pmsk[n * KC_ + kc]) continue;        // uniform across block
    const int c = pidx[n * KC_ + kc];
    __syncthreads();                           // prev PV done (and q visible on 1st iter)
    {
      const size_t base = ((size_t)(b * S_ + c * 64 + qrow) * D_) + h * 64 + e0;
      load16(kb + base, 1.0f, &ks[qrow][e0]);
      load16(vb + base, 1.0f, &vs[qrow][e0]);
    }
    __syncthreads();

    // scores for 16 keys (quarter), row qrow
    float sacc[16];
#pragma unroll
    for (int kk = 0; kk < 16; kk++) sacc[kk] = 0.0f;
    for (int e = 0; e < 64; e++) {
      const float qv = qs[qrow][e];
#pragma unroll
      for (int kk = 0; kk < 16; kk++) sacc[kk] += qv * ks[e0 + kk][e];
    }

    float bmax = -1e30f;
    const int sb = b * S_ + c * 64 + e0;
#pragma unroll
    for (int kk = 0; kk < 16; kk++) {
      if (tokens[sb + kk] <= 0) sacc[kk] = -1e30f;
      bmax = fmaxf(bmax, sacc[kk]);
    }
    bmax = fmaxf(bmax, __shfl_xor(bmax, 1));
    bmax = fmaxf(bmax, __shfl_xor(bmax, 2));

    const float mnew = fmaxf(mrow, bmax);
    const float alpha = expf(mrow - mnew);     // 0 on first valid block, 1 if no change
    float psum = 0.0f;
#pragma unroll
    for (int kk = 0; kk < 16; kk++) {
      const float p = (sacc[kk] > -1e29f) ? expf(sacc[kk] - mnew) : 0.0f;
      ps[qrow][e0 + kk] = p;
      psum += p;
    }
    psum += __shfl_xor(psum, 1);
    psum += __shfl_xor(psum, 2);
    ssum = ssum * alpha + psum;
    mrow = mnew;
#pragma unroll
    for (int j = 0; j < 16; j++) o[j] *= alpha;
    __syncthreads();                           // ps visible

    for (int key = 0; key < 64; key++) {
      const float p = ps[qrow][key];
      const float4* vrow = (const float4*)&vs[key][e0];
#pragma unroll
      for (int jj = 0; jj < 4; jj++) {
        float4 vv = vrow[jj];
        o[jj * 4 + 0] += p * vv.x;
        o[jj * 4 + 1] += p * vv.y;
        o[jj * 4 + 2] += p * vv.z;
        o[jj * 4 + 3] += p * vv.w;
      }
    }
  }

  const float inv = (ssum > 0.0f) ? (1.0f / ssum) : 0.0f;
  u16 tmp[16];
#pragma unroll
  for (int j = 0; j < 16; j++) tmp[j] = f2b(o[j] * inv);
  uint4* dst = (uint4*)(outb + ((size_t)(b * S_ + n * 64 + qrow) * D_) + h * 64 + e0);
  dst[0] = *(const uint4*)&tmp[0];
  dst[1] = *(const uint4*)&tmp[8];
}

// ---------- host orchestration ----------
extern "C" void kernel_launch(void* const* d_in, const int* in_sizes, int n_in,
                              void* d_out, int out_size, void* d_ws, size_t ws_size,
                              hipStream_t stream) {
  (void)in_sizes; (void)n_in; (void)out_size; (void)ws_size;

  const int*   tokens = (const int*)d_in[0];
  const float* embed  = (const float*)d_in[1];
  const float* ln1_s  = (const float*)d_in[2];
  const float* ln1_b  = (const float*)d_in[3];
  const float* wq     = (const float*)d_in[4];
  const float* wk     = (const float*)d_in[5];
  const float* wv     = (const float*)d_in[6];
  const float* wo     = (const float*)d_in[7];
  const float* ln2_s  = (const float*)d_in[8];
  const float* ln2_b  = (const float*)d_in[9];
  const float* w1     = (const float*)d_in[10];
  const float* b1     = (const float*)d_in[11];
  const float* w2     = (const float*)d_in[12];
  const float* b2     = (const float*)d_in[13];
  const float* lnf_s  = (const float*)d_in[14];
  const float* lnf_b  = (const float*)d_in[15];

  char* wp = (char*)d_ws;
  auto take = [&](size_t bytes) {
    void* p = (void*)wp;
    wp += (bytes + 255) & ~(size_t)255;
    return p;
  };

  int* pidx  = (int*)take((size_t)L_ * NB_ * KC_ * 4);
  int* pmsk  = (int*)take((size_t)L_ * NB_ * KC_ * 4);
  u16* wqT   = (u16*)take((size_t)L_ * D_ * D_ * 2);
  u16* wkT   = (u16*)take((size_t)L_ * D_ * D_ * 2);
  u16* wvT   = (u16*)take((size_t)L_ * D_ * D_ * 2);
  u16* woT   = (u16*)take((size_t)L_ * D_ * D_ * 2);
  u16* w1T   = (u16*)take((size_t)L_ * FF_ * D_ * 2);
  u16* w2T   = (u16*)take((size_t)L_ * D_ * FF_ * 2);
  float* x   = (float*)take((size_t)B_ * S_ * D_ * 4);
  u16* h     = (u16*)take((size_t)B_ * S_ * D_ * 2);
  u16* qbuf  = (u16*)take((size_t)B_ * S_ * D_ * 2);
  u16* kbuf  = (u16*)take((size_t)B_ * S_ * D_ * 2);
  u16* vbuf  = (u16*)take((size_t)B_ * S_ * D_ * 2);
  u16* g     = (u16*)take((size_t)B_ * S_ * FF_ * 2);

  const int Mrows = B_ * S_;

  plan_kernel<<<1, 64, 0, stream>>>(pidx, pmsk);
  transpose_conv<<<dim3(D_ / 32, D_ / 32, L_), dim3(32, 8), 0, stream>>>(wq, wqT, D_, D_);
  transpose_conv<<<dim3(D_ / 32, D_ / 32, L_), dim3(32, 8), 0, stream>>>(wk, wkT, D_, D_);
  transpose_conv<<<dim3(D_ / 32, D_ / 32, L_), dim3(32, 8), 0, stream>>>(wv, wvT, D_, D_);
  transpose_conv<<<dim3(D_ / 32, D_ / 32, L_), dim3(32, 8), 0, stream>>>(wo, woT, D_, D_);
  transpose_conv<<<dim3(FF_ / 32, D_ / 32, L_), dim3(32, 8), 0, stream>>>(w1, w1T, D_, FF_);
  transpose_conv<<<dim3(D_ / 32, FF_ / 32, L_), dim3(32, 8), 0, stream>>>(w2, w2T, FF_, D_);
  embed_kernel<<<Mrows, 128, 0, stream>>>(tokens, embed, x);

  for (int l = 0; l < L_; l++) {
    ln_kernel<true><<<Mrows, 128, 0, stream>>>(x, ln1_s + l * D_, ln1_b + l * D_, h);
    gemm_bt<0><<<dim3(Mrows / 128, D_ / 128), 256, 0, stream>>>(
        h, wqT + (size_t)l * D_ * D_, Mrows, D_, D_, nullptr, qbuf, nullptr, nullptr);
    gemm_bt<0><<<dim3(Mrows / 128, D_ / 128), 256, 0, stream>>>(
        h, wkT + (size_t)l * D_ * D_, Mrows, D_, D_, nullptr, kbuf, nullptr, nullptr);
    gemm_bt<0><<<dim3(Mrows / 128, D_ / 128), 256, 0, stream>>>(
        h, wvT + (size_t)l * D_ * D_, Mrows, D_, D_, nullptr, vbuf, nullptr, nullptr);
    attn_kernel<<<B_ * NB_ * H_, 256, 0, stream>>>(
        qbuf, kbuf, vbuf, tokens, pidx + l * NB_ * KC_, pmsk + l * NB_ * KC_, h);
    gemm_bt<1><<<dim3(Mrows / 128, D_ / 128), 256, 0, stream>>>(
        h, woT + (size_t)l * D_ * D_, Mrows, D_, D_, x, nullptr, nullptr, x);
    ln_kernel<true><<<Mrows, 128, 0, stream>>>(x, ln2_s + l * D_, ln2_b + l * D_, h);
    gemm_bt<2><<<dim3(Mrows / 128, FF_ / 128), 256, 0, stream>>>(
        h, w1T + (size_t)l * FF_ * D_, Mrows, FF_, D_, nullptr, g, b1 + l * FF_, nullptr);
    gemm_bt<3><<<dim3(Mrows / 128, D_ / 128), 256, 0, stream>>>(
        g, w2T + (size_t)l * D_ * FF_, Mrows, D_, FF_, x, nullptr, b2 + l * D_, x);
  }
  ln_kernel<false><<<Mrows, 128, 0, stream>>>(x, lnf_s, lnf_b, d_out);
}

// Round 2
// 1115.484 us; speedup vs baseline: 3.5481x; 3.5481x over previous
//
#include <hip/hip_runtime.h>

using u32 = unsigned int;
using u16 = unsigned short;

#define B_   4
#define S_   2048
#define D_   512
#define H_   8
#define DH_  64
#define FF_  2048
#define L_   6
#define NB_  32
#define KC_  8

typedef __attribute__((ext_vector_type(8))) __bf16 bf16x8;
typedef __attribute__((ext_vector_type(4))) float  f32x4;

struct Plan { unsigned char idx[NB_][KC_]; unsigned char cnt[NB_]; };

// ---------- helpers ----------
__device__ __forceinline__ u16 f2b(float f) {
  union { float f; u32 u; } x; x.f = f;
  u32 u = x.u;
  u32 r = (u + 0x7fffu + ((u >> 16) & 1u)) >> 16;
  return (u16)r;
}

__device__ __forceinline__ float gelu_f(float x) {
  return 0.5f * x * (1.0f + tanhf(0.7978845608028654f * (x + 0.044715f * x * x * x)));
}

// async global->LDS 16B per lane. dst must be the wave-uniform base (lane 0 slot);
// HW writes lane l at dst + l*16B.
typedef const __attribute__((address_space(1))) u32* gas_t;
typedef __attribute__((address_space(3))) u32* las_t;
__device__ __forceinline__ void glds16(const u16* g, u16* l) {
  __builtin_amdgcn_global_load_lds((gas_t)g, (las_t)l, 16, 0, 0);
}

// ---------- weight transpose-convert: in f32 [L][R][C] -> out bf16 rows=C cols=R ----------
__global__ __launch_bounds__(256)
void transpose_conv(const float* __restrict__ in, u16* __restrict__ out, int R, int C,
                    size_t lstride, int rowoff) {
  __shared__ float tile[32][33];
  const int l = blockIdx.z;
  const float* src = in + (size_t)l * R * C;
  u16* dst = out + (size_t)l * lstride;
  const int c0 = blockIdx.x * 32, r0 = blockIdx.y * 32;
  const int tx = threadIdx.x, ty = threadIdx.y;
#pragma unroll
  for (int i = 0; i < 4; i++)
    tile[ty + i * 8][tx] = src[(size_t)(r0 + ty + i * 8) * C + c0 + tx];
  __syncthreads();
#pragma unroll
  for (int i = 0; i < 4; i++)
    dst[(size_t)(rowoff + c0 + ty + i * 8) * R + r0 + tx] = f2b(tile[tx][ty + i * 8]);
}

// ---------- embedding + sinusoidal pos ----------
__global__ __launch_bounds__(128)
void embed_kernel(const int* __restrict__ tokens, const float* __restrict__ emb,
                  float* __restrict__ x) {
  const int row = blockIdx.x;           // b*S + s
  const int s = row & (S_ - 1);
  const int t = threadIdx.x;
  const int tok = tokens[row];
  float4 v = ((const float4*)(emb + (size_t)tok * D_))[t];
  float va[4] = {v.x, v.y, v.z, v.w};
  const float cc = -2.0f * logf(10000.0f) / (float)D_;
  const float pos = (float)s;
#pragma unroll
  for (int j = 0; j < 4; j++) {
    int d = t * 4 + j;
    int i = d >> 1;
    float dv = expf(cc * (float)i);
    float ang = pos * dv;
    va[j] += (d & 1) ? cosf(ang) : sinf(ang);
  }
  ((float4*)x)[(size_t)row * (D_ / 4) + t] = make_float4(va[0], va[1], va[2], va[3]);
}

// ---------- layernorm: f32 in -> bf16 (or f32) out ----------
template <bool BF16OUT>
__global__ __launch_bounds__(128)
void ln_kernel(const float* __restrict__ x, const float* __restrict__ sc,
               const float* __restrict__ bi, void* __restrict__ outp) {
  const int row = blockIdx.x;
  const int t = threadIdx.x;
  float4 v = ((const float4*)(x + (size_t)row * D_))[t];
  float va[4] = {v.x, v.y, v.z, v.w};
  float s = va[0] + va[1] + va[2] + va[3];
  float sq = va[0] * va[0] + va[1] * va[1] + va[2] * va[2] + va[3] * va[3];
#pragma unroll
  for (int d = 1; d < 64; d <<= 1) {
    s  += __shfl_xor(s, d);
    sq += __shfl_xor(sq, d);
  }
  __shared__ float red[4];
  const int wv = t >> 6, lane = t & 63;
  if (lane == 0) { red[wv * 2] = s; red[wv * 2 + 1] = sq; }
  __syncthreads();
  const float ts  = red[0] + red[2];
  const float tsq = red[1] + red[3];
  const float mean = ts * (1.0f / (float)D_);
  const float inv  = rsqrtf(tsq * (1.0f / (float)D_) - mean * mean + 1e-6f);
  const int d0 = t * 4;
  float o[4];
#pragma unroll
  for (int j = 0; j < 4; j++)
    o[j] = (va[j] - mean) * inv * sc[d0 + j] + bi[d0 + j];
  if (BF16OUT) {
    ushort4 u;
    u.x = f2b(o[0]); u.y = f2b(o[1]); u.z = f2b(o[2]); u.w = f2b(o[3]);
    ((ushort4*)outp)[(size_t)row * (D_ / 4) + t] = u;
  } else {
    ((float4*)outp)[(size_t)row * (D_ / 4) + t] = make_float4(o[0], o[1], o[2], o[3]);
  }
}

// ---------- bf16 MFMA GEMM:  C[M,N] = A[M,K] * BT[N,K]^T  (+ epilogue) ----------
// MODE 0: out bf16
// MODE 1: out f32 = acc + resid
// MODE 2: out bf16 = gelu(acc + bias)
// MODE 3: out f32 = acc + bias + resid
template <int MODE, int BN>
__global__ __launch_bounds__(256)
void gemm_bt(const u16* __restrict__ A, const u16* __restrict__ BT,
             int Nn, int Kk,
             float* __restrict__ outf, u16* __restrict__ outb,
             const float* __restrict__ bias, const float* __restrict__ resid) {
  constexpr int MI = (BN == 128) ? 4 : 2;   // per-wave 16-row tiles
  __shared__ u16 As[128 * 32];
  __shared__ u16 Bs[BN * 32];
  const int tid = threadIdx.x;
  const int wave = tid >> 6, lane = tid & 63;
  const int row0 = blockIdx.x * 128, col0 = blockIdx.y * BN;
  const int wr = (BN == 128) ? (wave >> 1) : wave;
  const int wc = (BN == 128) ? (wave & 1) : 0;
  const int l15 = lane & 15, l4 = lane >> 4;
  f32x4 acc[MI][4] = {};

  for (int k0 = 0; k0 < Kk; k0 += 32) {
    __syncthreads();
#pragma unroll
    for (int i = 0; i < 2; i++) {
      int c0 = wave * 128 + i * 64;
      int cl = c0 + lane;
      glds16(A + (size_t)(row0 + (cl >> 2)) * Kk + k0 + ((cl & 3) << 3), As + c0 * 8);
    }
#pragma unroll
    for (int i = 0; i < BN / 64; i++) {
      int c0 = wave * BN + i * 64;
      int cl = c0 + lane;
      glds16(BT + (size_t)(col0 + (cl >> 2)) * Kk + k0 + ((cl & 3) << 3), Bs + c0 * 8);
    }
    __syncthreads();
    bf16x8 af[MI], bfr[4];
#pragma unroll
    for (int m = 0; m < MI; m++)
      af[m] = *(const bf16x8*)(As + (wr * (MI * 16) + m * 16 + l15) * 32 + l4 * 8);
#pragma unroll
    for (int n = 0; n < 4; n++)
      bfr[n] = *(const bf16x8*)(Bs + (wc * 64 + n * 16 + l15) * 32 + l4 * 8);
#pragma unroll
    for (int m = 0; m < MI; m++)
#pragma unroll
      for (int n = 0; n < 4; n++)
        acc[m][n] = __builtin_amdgcn_mfma_f32_16x16x32_bf16(af[m], bfr[n], acc[m][n], 0, 0, 0);
  }

#pragma unroll
  for (int m = 0; m < MI; m++) {
#pragma unroll
    for (int n = 0; n < 4; n++) {
#pragma unroll
      for (int j = 0; j < 4; j++) {
        const int r = row0 + wr * (MI * 16) + m * 16 + l4 * 4 + j;
        const int c = col0 + wc * 64 + n * 16 + l15;
        const size_t o = (size_t)r * Nn + c;
        float v = acc[m][n][j];
        if (MODE == 0) {
          outb[o] = f2b(v);
        } else if (MODE == 1) {
          outf[o] = v + resid[o];
        } else if (MODE == 2) {
          outb[o] = f2b(gelu_f(v + bias[c]));
        } else {
          outf[o] = v + bias[c] + resid[o];
        }
      }
    }
  }
}

// ---------- MFMA block-sparse attention ----------
// One wg per (b, block n, head h): 4 waves, wave w owns q rows [w*16, w*16+16).
// qkv layout: [B*S][1536] bf16, q|k|v at col offsets 0|512|1024, head at h*64.
// LDS tiles stride 64 u16 = 128B rows with XOR swizzle: u16 idx = row*64 + (col ^ ((row&7)<<3)).
__global__ __launch_bounds__(256)
void attn_mfma(const u16* __restrict__ qkv, const int* __restrict__ tokens,
               u16* __restrict__ outb, Plan plan) {
  __shared__ u16 qs[64 * 64];
  __shared__ u16 ks[64 * 64];
  __shared__ u16 vt[64 * 64];   // transposed V: rows = dh, cols = keys
  __shared__ u16 ps[64 * 64];   // P tile (per-wave private rows)
  __shared__ unsigned char km[KC_ * 64];

  const int blk = blockIdx.x;
  const int h0 = blk & 7;
  const int n  = (blk >> 3) & 31;
  const int b  = blk >> 8;
  const int t  = threadIdx.x;
  const int wave = t >> 6, lane = t & 63;
  const int l15 = lane & 15, l4 = lane >> 4;

  const int ncnt = plan.cnt[n];
  const size_t rowbase = (size_t)(b * S_ + n * 64) * 1536;

  // stage Q via glds with pre-swizzled source (rule 21: linear dst + inv-swz src)
#pragma unroll
  for (int i = 0; i < 2; i++) {
    int c0 = i * 256 + wave * 64;
    int cl = c0 + lane;
    int r = cl >> 3;
    int gc = ((cl & 7) ^ (r & 7)) << 3;
    glds16(qkv + rowbase + (size_t)r * 1536 + h0 * 64 + gc, qs + c0 * 8);
  }
  // combined key-validity mask for all gathered blocks
#pragma unroll
  for (int i = 0; i < 2; i++) {
    int e = t + i * 256;
    int kc = e >> 6, col = e & 63;
    int c = plan.idx[n][kc];
    km[e] = (kc < ncnt) && (tokens[b * S_ + c * 64 + col] > 0);
  }
  __syncthreads();

  // loop-invariant Q A-frags (row = wave*16 + l15, dh slice l4*8 within 32-step)
  bf16x8 qaf[2];
#pragma unroll
  for (int ks_ = 0; ks_ < 2; ks_++) {
    int r = wave * 16 + l15;
    qaf[ks_] = *(const bf16x8*)(qs + r * 64 + ((ks_ * 32 + l4 * 8) ^ ((r & 7) << 3)));
  }

  f32x4 oacc[4] = {};
  float mrow[4], lrow[4];
#pragma unroll
  for (int j = 0; j < 4; j++) { mrow[j] = -3e38f; lrow[j] = 0.0f; }

  for (int kc = 0; kc < ncnt; kc++) {
    const int c = plan.idx[n][kc];
    const size_t kvbase = (size_t)(b * S_ + c * 64) * 1536;
    __syncthreads();   // prior iteration's K/V reads done

    // stage K (glds, pre-swizzled source)
#pragma unroll
    for (int i = 0; i < 2; i++) {
      int c0 = i * 256 + wave * 64;
      int cl = c0 + lane;
      int r = cl >> 3;
      int gc = ((cl & 7) ^ (r & 7)) << 3;
      glds16(qkv + kvbase + (size_t)r * 1536 + 512 + h0 * 64 + gc, ks + c0 * 8);
    }
    // stage V transposed (reg-staged, swizzled scatter)
#pragma unroll
    for (int i = 0; i < 2; i++) {
      int cl = t + i * 256;
      int k = cl >> 3, c8 = (cl & 7) << 3;
      uint4 vv = *(const uint4*)(qkv + kvbase + (size_t)k * 1536 + 1024 + h0 * 64 + c8);
      u16 tmpv[8];
      *(uint4*)tmpv = vv;
#pragma unroll
      for (int j = 0; j < 8; j++) {
        int e = c8 + j;
        vt[e * 64 + (k ^ ((e & 7) << 3))] = tmpv[j];
      }
    }
    __syncthreads();

    // QK^T: S[16q x 64k] per wave
    f32x4 sacc[4] = {};
#pragma unroll
    for (int nn = 0; nn < 4; nn++) {
#pragma unroll
      for (int ks_ = 0; ks_ < 2; ks_++) {
        int r = nn * 16 + l15;
        bf16x8 kf = *(const bf16x8*)(ks + r * 64 + ((ks_ * 32 + l4 * 8) ^ ((r & 7) << 3)));
        sacc[nn] = __builtin_amdgcn_mfma_f32_16x16x32_bf16(qaf[ks_], kf, sacc[nn], 0, 0, 0);
      }
    }

    // key validity (per column)
    bool vld[4];
#pragma unroll
    for (int nn = 0; nn < 4; nn++) vld[nn] = km[kc * 64 + nn * 16 + l15] != 0;

    // online softmax; rows per lane: q = wave*16 + l4*4 + j (16-lane row groups)
    float p[4][4], rmax[4], alpha[4];
#pragma unroll
    for (int j = 0; j < 4; j++) {
      float mj = -3e38f;
#pragma unroll
      for (int nn = 0; nn < 4; nn++) {
        float sv = sacc[nn][j] * 0.125f;
        p[nn][j] = sv;
        if (vld[nn]) mj = fmaxf(mj, sv);
      }
      rmax[j] = mj;
    }
#pragma unroll
    for (int d = 1; d < 16; d <<= 1) {
#pragma unroll
      for (int j = 0; j < 4; j++) rmax[j] = fmaxf(rmax[j], __shfl_xor(rmax[j], d));
    }
#pragma unroll
    for (int j = 0; j < 4; j++) {
      float mn = fmaxf(mrow[j], rmax[j]);
      alpha[j] = __expf(mrow[j] - mn);
      mrow[j] = mn;
      float psum = 0.0f;
#pragma unroll
      for (int nn = 0; nn < 4; nn++) {
        float pv = vld[nn] ? __expf(p[nn][j] - mn) : 0.0f;
        p[nn][j] = pv;
        psum += pv;
      }
      lrow[j] = lrow[j] * alpha[j] + psum;  // lane-partial; reduced once at the end
    }
#pragma unroll
    for (int n2 = 0; n2 < 4; n2++)
#pragma unroll
      for (int j = 0; j < 4; j++) oacc[n2][j] *= alpha[j];

    // P -> bf16 -> LDS (wave-private rows; same-wave RAW needs no barrier)
#pragma unroll
    for (int nn = 0; nn < 4; nn++)
#pragma unroll
      for (int j = 0; j < 4; j++) {
        int q = wave * 16 + l4 * 4 + j;
        ps[q * 64 + ((nn * 16 + l15) ^ ((q & 7) << 3))] = f2b(p[nn][j]);
      }

    // PV: O[16q x 64dh] += P[16x64] * V[64x64]
#pragma unroll
    for (int ks_ = 0; ks_ < 2; ks_++) {
      int r = wave * 16 + l15;
      bf16x8 paf = *(const bf16x8*)(ps + r * 64 + ((ks_ * 32 + l4 * 8) ^ ((r & 7) << 3)));
#pragma unroll
      for (int n2 = 0; n2 < 4; n2++) {
        int rv = n2 * 16 + l15;
        bf16x8 vf = *(const bf16x8*)(vt + rv * 64 + ((ks_ * 32 + l4 * 8) ^ ((rv & 7) << 3)));
        oacc[n2] = __builtin_amdgcn_mfma_f32_16x16x32_bf16(paf, vf, oacc[n2], 0, 0, 0);
      }
    }
  }

  // reduce row sums across the 16-lane row group, normalize, store
#pragma unroll
  for (int d = 1; d < 16; d <<= 1) {
#pragma unroll
    for (int j = 0; j < 4; j++) lrow[j] += __shfl_xor(lrow[j], d);
  }
#pragma unroll
  for (int j = 0; j < 4; j++) {
    const float inv = lrow[j] > 0.0f ? 1.0f / lrow[j] : 0.0f;
    const int q = n * 64 + wave * 16 + l4 * 4 + j;
#pragma unroll
    for (int n2 = 0; n2 < 4; n2++) {
      outb[(size_t)(b * S_ + q) * D_ + h0 * 64 + n2 * 16 + l15] = f2b(oacc[n2][j] * inv);
    }
  }
}

// ---------- host-side exact numpy RandomState(MT19937) plan ----------
namespace {
struct HostMT {
  u32 mt[624]; int mti;
  void seed(u32 s) {
    mt[0] = s;
    for (int i = 1; i < 624; i++)
      mt[i] = 1812433253u * (mt[i - 1] ^ (mt[i - 1] >> 30)) + (u32)i;
    mti = 624;
  }
  u32 next() {
    if (mti >= 624) {
      for (int k = 0; k < 624; k++) {
        u32 y = (mt[k] & 0x80000000u) | (mt[(k + 1) % 624] & 0x7fffffffu);
        mt[k] = mt[(k + 397) % 624] ^ (y >> 1) ^ ((y & 1u) ? 0x9908b0dfu : 0u);
      }
      mti = 0;
    }
    u32 y = mt[mti++];
    y ^= y >> 11;
    y ^= (y << 7)  & 0x9d2c5680u;
    y ^= (y << 15) & 0xefc60000u;
    y ^= y >> 18;
    return y;
  }
  u32 interval(u32 mx) {
    if (mx == 0u) return 0u;
    u32 mask = mx;
    mask |= mask >> 1; mask |= mask >> 2; mask |= mask >> 4;
    mask |= mask >> 8; mask |= mask >> 16;
    u32 v;
    while ((v = (next() & mask)) > mx) {}
    return v;
  }
};

void build_plan(int l, Plan* out) {
  HostMT rng;
  rng.seed((u32)l);
  for (int i = 0; i < NB_; i++) {
    bool fixedv[NB_] = {};
    fixedv[0] = true; fixedv[NB_ - 1] = true;
    for (int j = i - 1; j <= i + 1; j++)
      if (j >= 0 && j < NB_) fixedv[j] = true;
    int rest[NB_]; int nr = 0;
    for (int j = 0; j < NB_; j++) if (!fixedv[j]) rest[nr++] = j;
    int perm[NB_];
    for (int tt = 0; tt < nr; tt++) perm[tt] = tt;
    for (int tt = nr - 1; tt >= 1; tt--) {
      int j = (int)rng.interval((u32)tt);
      int tmp = perm[tt]; perm[tt] = perm[j]; perm[j] = tmp;
    }
    bool sel[NB_];
    for (int j = 0; j < NB_; j++) sel[j] = fixedv[j];
    for (int c = 0; c < 3; c++) sel[rest[perm[c]]] = true;
    int cnt = 0;
    for (int j = 0; j < NB_; j++)
      if (sel[j]) out->idx[i][cnt++] = (unsigned char)j;
    out->cnt[i] = (unsigned char)cnt;
    for (int c2 = cnt; c2 < KC_; c2++) out->idx[i][c2] = 0;
  }
}
}  // namespace

// ---------- host orchestration ----------
extern "C" void kernel_launch(void* const* d_in, const int* in_sizes, int n_in,
                              void* d_out, int out_size, void* d_ws, size_t ws_size,
                              hipStream_t stream) {
  (void)in_sizes; (void)n_in; (void)out_size; (void)ws_size;

  const int*   tokens = (const int*)d_in[0];
  const float* embed  = (const float*)d_in[1];
  const float* ln1_s  = (const float*)d_in[2];
  const float* ln1_b  = (const float*)d_in[3];
  const float* wq     = (const float*)d_in[4];
  const float* wk     = (const float*)d_in[5];
  const float* wv     = (const float*)d_in[6];
  const float* wo     = (const float*)d_in[7];
  const float* ln2_s  = (const float*)d_in[8];
  const float* ln2_b  = (const float*)d_in[9];
  const float* w1     = (const float*)d_in[10];
  const float* b1     = (const float*)d_in[11];
  const float* w2     = (const float*)d_in[12];
  const float* b2     = (const float*)d_in[13];
  const float* lnf_s  = (const float*)d_in[14];
  const float* lnf_b  = (const float*)d_in[15];

  char* wp = (char*)d_ws;
  auto take = [&](size_t bytes) {
    void* p = (void*)wp;
    wp += (bytes + 255) & ~(size_t)255;
    return p;
  };

  u16* wqkvT = (u16*)take((size_t)L_ * 1536 * D_ * 2);   // [L][1536][512]
  u16* woT   = (u16*)take((size_t)L_ * D_ * D_ * 2);     // [L][512][512]
  u16* w1T   = (u16*)take((size_t)L_ * FF_ * D_ * 2);    // [L][2048][512]
  u16* w2T   = (u16*)take((size_t)L_ * D_ * FF_ * 2);    // [L][512][2048]
  float* x   = (float*)take((size_t)B_ * S_ * D_ * 4);
  u16* h     = (u16*)take((size_t)B_ * S_ * D_ * 2);
  u16* big   = (u16*)take((size_t)B_ * S_ * FF_ * 2);    // qkv (25MB) / g (34MB), time-shared
  u16* qkv   = big;
  u16* g     = big;

  Plan plans[L_];
  for (int l = 0; l < L_; l++) build_plan(l, &plans[l]);

  const int Mrows = B_ * S_;
  const size_t qkvL = (size_t)1536 * D_;

  transpose_conv<<<dim3(D_ / 32, D_ / 32, L_), dim3(32, 8), 0, stream>>>(wq, wqkvT, D_, D_, qkvL, 0);
  transpose_conv<<<dim3(D_ / 32, D_ / 32, L_), dim3(32, 8), 0, stream>>>(wk, wqkvT, D_, D_, qkvL, 512);
  transpose_conv<<<dim3(D_ / 32, D_ / 32, L_), dim3(32, 8), 0, stream>>>(wv, wqkvT, D_, D_, qkvL, 1024);
  transpose_conv<<<dim3(D_ / 32, D_ / 32, L_), dim3(32, 8), 0, stream>>>(wo, woT, D_, D_, (size_t)D_ * D_, 0);
  transpose_conv<<<dim3(FF_ / 32, D_ / 32, L_), dim3(32, 8), 0, stream>>>(w1, w1T, D_, FF_, (size_t)FF_ * D_, 0);
  transpose_conv<<<dim3(D_ / 32, FF_ / 32, L_), dim3(32, 8), 0, stream>>>(w2, w2T, FF_, D_, (size_t)D_ * FF_, 0);
  embed_kernel<<<Mrows, 128, 0, stream>>>(tokens, embed, x);

  for (int l = 0; l < L_; l++) {
    ln_kernel<true><<<Mrows, 128, 0, stream>>>(x, ln1_s + l * D_, ln1_b + l * D_, h);
    gemm_bt<0, 128><<<dim3(Mrows / 128, 1536 / 128), 256, 0, stream>>>(
        h, wqkvT + (size_t)l * qkvL, 1536, D_, nullptr, qkv, nullptr, nullptr);
    attn_mfma<<<B_ * NB_ * H_, 256, 0, stream>>>(qkv, tokens, h, plans[l]);
    gemm_bt<1, 64><<<dim3(Mrows / 128, D_ / 64), 256, 0, stream>>>(
        h, woT + (size_t)l * D_ * D_, D_, D_, x, nullptr, nullptr, x);
    ln_kernel<true><<<Mrows, 128, 0, stream>>>(x, ln2_s + l * D_, ln2_b + l * D_, h);
    gemm_bt<2, 128><<<dim3(Mrows / 128, FF_ / 128), 256, 0, stream>>>(
        h, w1T + (size_t)l * FF_ * D_, FF_, D_, nullptr, g, b1 + l * FF_, nullptr);
    gemm_bt<3, 64><<<dim3(Mrows / 128, D_ / 64), 256, 0, stream>>>(
        g, w2T + (size_t)l * D_ * FF_, D_, FF_, x, nullptr, b2 + l * D_, x);
  }
  ln_kernel<false><<<Mrows, 128, 0, stream>>>(x, lnf_s, lnf_b, d_out);
}

// Round 3
// 930.127 us; speedup vs baseline: 4.2551x; 1.1993x over previous
//
#include <hip/hip_runtime.h>

using u32 = unsigned int;
using u16 = unsigned short;

#define B_   4
#define S_   2048
#define D_   512
#define H_   8
#define DH_  64
#define FF_  2048
#define L_   6
#define NB_  32
#define KC_  8

typedef __attribute__((ext_vector_type(8))) __bf16 bf16x8;
typedef __attribute__((ext_vector_type(4))) float  f32x4;

struct Plan { unsigned char idx[NB_][KC_]; unsigned char cnt[NB_]; };

// ---------- helpers ----------
__device__ __forceinline__ u16 f2b(float f) {
  union { float f; u32 u; } x; x.f = f;
  u32 u = x.u;
  u32 r = (u + 0x7fffu + ((u >> 16) & 1u)) >> 16;
  return (u16)r;
}

// exact tanh-gelu via sigmoid identity: 0.5*(1+tanh(y)) == 1/(1+e^{-2y})
__device__ __forceinline__ float gelu_f(float x) {
  float y2 = 1.5957691216f * x + 0.0713548163f * x * x * x;  // 2*y
  return x / (1.0f + __expf(-y2));
}

// async global->LDS 16B per lane. dst = wave-uniform base; lane l lands at +l*16B.
typedef const __attribute__((address_space(1))) u32* gas_t;
typedef __attribute__((address_space(3))) u32* las_t;
__device__ __forceinline__ void glds16(const u16* g, u16* l) {
  __builtin_amdgcn_global_load_lds((gas_t)g, (las_t)l, 16, 0, 0);
}

// ---------- weight transpose-convert: in f32 [L][R][C] -> out bf16 rows=C cols=R ----------
__global__ __launch_bounds__(256)
void transpose_conv(const float* __restrict__ in, u16* __restrict__ out, int R, int C,
                    size_t lstride, int rowoff) {
  __shared__ float tile[32][33];
  const int l = blockIdx.z;
  const float* src = in + (size_t)l * R * C;
  u16* dst = out + (size_t)l * lstride;
  const int c0 = blockIdx.x * 32, r0 = blockIdx.y * 32;
  const int tx = threadIdx.x, ty = threadIdx.y;
#pragma unroll
  for (int i = 0; i < 4; i++)
    tile[ty + i * 8][tx] = src[(size_t)(r0 + ty + i * 8) * C + c0 + tx];
  __syncthreads();
#pragma unroll
  for (int i = 0; i < 4; i++)
    dst[(size_t)(rowoff + c0 + ty + i * 8) * R + r0 + tx] = f2b(tile[tx][ty + i * 8]);
}

// ---------- embedding + sinusoidal pos ----------
__global__ __launch_bounds__(128)
void embed_kernel(const int* __restrict__ tokens, const float* __restrict__ emb,
                  float* __restrict__ x) {
  const int row = blockIdx.x;           // b*S + s
  const int s = row & (S_ - 1);
  const int t = threadIdx.x;
  const int tok = tokens[row];
  float4 v = ((const float4*)(emb + (size_t)tok * D_))[t];
  float va[4] = {v.x, v.y, v.z, v.w};
  const float cc = -2.0f * logf(10000.0f) / (float)D_;
  const float pos = (float)s;
#pragma unroll
  for (int j = 0; j < 4; j++) {
    int d = t * 4 + j;
    int i = d >> 1;
    float dv = expf(cc * (float)i);
    float ang = pos * dv;
    va[j] += (d & 1) ? cosf(ang) : sinf(ang);
  }
  ((float4*)x)[(size_t)row * (D_ / 4) + t] = make_float4(va[0], va[1], va[2], va[3]);
}

// ---------- layernorm: f32 in -> bf16 (or f32) out ----------
template <bool BF16OUT>
__global__ __launch_bounds__(128)
void ln_kernel(const float* __restrict__ x, const float* __restrict__ sc,
               const float* __restrict__ bi, void* __restrict__ outp) {
  const int row = blockIdx.x;
  const int t = threadIdx.x;
  float4 v = ((const float4*)(x + (size_t)row * D_))[t];
  float va[4] = {v.x, v.y, v.z, v.w};
  float s = va[0] + va[1] + va[2] + va[3];
  float sq = va[0] * va[0] + va[1] * va[1] + va[2] * va[2] + va[3] * va[3];
#pragma unroll
  for (int d = 1; d < 64; d <<= 1) {
    s  += __shfl_xor(s, d);
    sq += __shfl_xor(sq, d);
  }
  __shared__ float red[4];
  const int wv = t >> 6, lane = t & 63;
  if (lane == 0) { red[wv * 2] = s; red[wv * 2 + 1] = sq; }
  __syncthreads();
  const float ts  = red[0] + red[2];
  const float tsq = red[1] + red[3];
  const float mean = ts * (1.0f / (float)D_);
  const float inv  = rsqrtf(tsq * (1.0f / (float)D_) - mean * mean + 1e-6f);
  const int d0 = t * 4;
  float o[4];
#pragma unroll
  for (int j = 0; j < 4; j++)
    o[j] = (va[j] - mean) * inv * sc[d0 + j] + bi[d0 + j];
  if (BF16OUT) {
    ushort4 u;
    u.x = f2b(o[0]); u.y = f2b(o[1]); u.z = f2b(o[2]); u.w = f2b(o[3]);
    ((ushort4*)outp)[(size_t)row * (D_ / 4) + t] = u;
  } else {
    ((float4*)outp)[(size_t)row * (D_ / 4) + t] = make_float4(o[0], o[1], o[2], o[3]);
  }
}

// ---------- bf16 MFMA GEMM, double-buffered BK=32, 1 barrier/iter ----------
// C[M,N] = A[M,K] * BT[N,K]^T  (+ epilogue)
// MODE 0: out bf16 (stride ostride); VSPLIT: cols>=1024 go transposed to vtout[c-1024][r]
// MODE 1: out f32 = acc + resid
// MODE 2: out bf16 = gelu(acc + bias)
// MODE 3: out f32 = acc + bias + resid
template <int MODE, int BN, bool VSPLIT>
__global__ __launch_bounds__(256)
void gemm_bt(const u16* __restrict__ A, const u16* __restrict__ BT,
             int Kk, int ostride,
             float* __restrict__ outf, u16* __restrict__ outb,
             const float* __restrict__ bias, const float* __restrict__ resid,
             u16* __restrict__ vtout) {
  constexpr int MI  = (BN == 128) ? 4 : 2;
  constexpr int BCH = BN / 64;                 // B-stage glds per wave
  __shared__ u16 As[2][128 * 32];
  __shared__ u16 Bs[2][BN * 32];
  const int tid = threadIdx.x;
  const int wave = tid >> 6, lane = tid & 63;
  const int row0 = blockIdx.x * 128, col0 = blockIdx.y * BN;
  const int wr = (BN == 128) ? (wave >> 1) : wave;
  const int wc = (BN == 128) ? (wave & 1) : 0;
  const int l15 = lane & 15, l4 = lane >> 4;

  // staging source pointers (per lane), k-slot XOR-swizzled (slot ^= (row>>1)&3)
  const u16* asrc[2];
  int adst[2];
#pragma unroll
  for (int i = 0; i < 2; i++) {
    int c0 = wave * 128 + i * 64;
    int cl = c0 + lane;
    int r = cl >> 2, s = cl & 3;
    asrc[i] = A + (size_t)(row0 + r) * Kk + ((s ^ ((r >> 1) & 3)) << 3);
    adst[i] = c0 * 8;
  }
  const u16* bsrc[BCH];
  int bdst[BCH];
#pragma unroll
  for (int i = 0; i < BCH; i++) {
    int c0 = wave * (BCH * 64) + i * 64;
    int cl = c0 + lane;
    int r = cl >> 2, s = cl & 3;
    bsrc[i] = BT + (size_t)(col0 + r) * Kk + ((s ^ ((r >> 1) & 3)) << 3);
    bdst[i] = c0 * 8;
  }

  // frag LDS offsets (u16 index); same swizzle on read side
  const int swz = (l4 ^ ((l15 >> 1) & 3)) << 3;
  int aoff[MI], boff[4];
#pragma unroll
  for (int m = 0; m < MI; m++) aoff[m] = (wr * (MI * 16) + m * 16 + l15) * 32 + swz;
#pragma unroll
  for (int n = 0; n < 4; n++)  boff[n] = (wc * 64 + n * 16 + l15) * 32 + swz;

  f32x4 acc[MI][4] = {};
  const int nk = Kk >> 5;

  // prologue: stage k-tile 0 into buf 0
#pragma unroll
  for (int i = 0; i < 2; i++) glds16(asrc[i], &As[0][adst[i]]);
#pragma unroll
  for (int i = 0; i < BCH; i++) glds16(bsrc[i], &Bs[0][bdst[i]]);

  for (int t = 0; t < nk; ++t) {
    const int cur = t & 1;
    __syncthreads();   // drains stage(t) glds + everyone's reads of buf[cur^1]
    if (t + 1 < nk) {
      const int ko = (t + 1) << 5;
#pragma unroll
      for (int i = 0; i < 2; i++) glds16(asrc[i] + ko, &As[cur ^ 1][adst[i]]);
#pragma unroll
      for (int i = 0; i < BCH; i++) glds16(bsrc[i] + ko, &Bs[cur ^ 1][bdst[i]]);
    }
    bf16x8 af[MI], bfr[4];
#pragma unroll
    for (int m = 0; m < MI; m++) af[m] = *(const bf16x8*)&As[cur][aoff[m]];
#pragma unroll
    for (int n = 0; n < 4; n++)  bfr[n] = *(const bf16x8*)&Bs[cur][boff[n]];
#pragma unroll
    for (int m = 0; m < MI; m++)
#pragma unroll
      for (int n = 0; n < 4; n++)
        acc[m][n] = __builtin_amdgcn_mfma_f32_16x16x32_bf16(af[m], bfr[n], acc[m][n], 0, 0, 0);
  }

#pragma unroll
  for (int m = 0; m < MI; m++) {
#pragma unroll
    for (int n = 0; n < 4; n++) {
      const int c = col0 + wc * 64 + n * 16 + l15;
      const int rb = row0 + wr * (MI * 16) + m * 16 + l4 * 4;
      if (VSPLIT && c >= 1024) {
        u16 pk[4];
#pragma unroll
        for (int j = 0; j < 4; j++) pk[j] = f2b(acc[m][n][j]);
        *(uint2*)(vtout + (size_t)(c - 1024) * (B_ * S_) + rb) = *(const uint2*)pk;
      } else {
#pragma unroll
        for (int j = 0; j < 4; j++) {
          const size_t o = (size_t)(rb + j) * ostride + c;
          float v = acc[m][n][j];
          if (MODE == 0) {
            outb[o] = f2b(v);
          } else if (MODE == 1) {
            outf[o] = v + resid[o];
          } else if (MODE == 2) {
            outb[o] = f2b(gelu_f(v + bias[c]));
          } else {
            outf[o] = v + bias[c] + resid[o];
          }
        }
      }
    }
  }
}

// ---------- MFMA block-sparse attention, K/V^T double-buffered prefetch ----------
// One wg per (b, block n, head h): 4 waves, wave w owns q rows [w*16, w*16+16).
// qkv: [B*S][1024] bf16 (q | k at col 0 | 512, head slice h*64). vT: [512][B*S] bf16.
// LDS row swizzle (128B rows): u16 idx = row*64 + (col ^ ((row&7)<<3)).
__global__ __launch_bounds__(256)
void attn_mfma(const u16* __restrict__ qkv, const u16* __restrict__ vTg,
               const int* __restrict__ tokens, u16* __restrict__ outb, Plan plan) {
  __shared__ u16 qs[64 * 64];
  __shared__ u16 ks[2][64 * 64];
  __shared__ u16 vt[2][64 * 64];
  __shared__ u16 ps[64 * 64];
  __shared__ unsigned char km[KC_ * 64];

  const int blk = blockIdx.x;
  const int h0 = blk & 7;
  const int n  = (blk >> 3) & 31;
  const int b  = blk >> 8;
  const int t  = threadIdx.x;
  const int wave = t >> 6, lane = t & 63;
  const int l15 = lane & 15, l4 = lane >> 4;
  const int ncnt = plan.cnt[n];
  const int qrow0 = b * S_ + n * 64;

  auto stage = [&](int bi, int c) {
    const int krow0 = b * S_ + c * 64;
#pragma unroll
    for (int i = 0; i < 2; i++) {
      int c0 = i * 256 + wave * 64;
      int cl = c0 + lane;
      int r = cl >> 3, s = cl & 7;
      int sw = (s ^ (r & 7)) << 3;
      glds16(qkv + (size_t)(krow0 + r) * 1024 + 512 + h0 * 64 + sw, &ks[bi][c0 * 8]);
      glds16(vTg + (size_t)(h0 * 64 + r) * (B_ * S_) + krow0 + sw, &vt[bi][c0 * 8]);
    }
  };

  // Q stage (swizzled source, linear LDS dst)
#pragma unroll
  for (int i = 0; i < 2; i++) {
    int c0 = i * 256 + wave * 64;
    int cl = c0 + lane;
    int r = cl >> 3, s = cl & 7;
    glds16(qkv + (size_t)(qrow0 + r) * 1024 + h0 * 64 + ((s ^ (r & 7)) << 3), qs + c0 * 8);
  }
  // key-validity mask for all gathered blocks
#pragma unroll
  for (int i = 0; i < 2; i++) {
    int e = t + i * 256;
    int kc = e >> 6, col = e & 63;
    int c = plan.idx[n][kc];
    km[e] = (kc < ncnt) && (tokens[b * S_ + c * 64 + col] > 0);
  }
  stage(0, plan.idx[n][0]);

  f32x4 oacc[4] = {};
  float mrow[4], lrow[4];
#pragma unroll
  for (int j = 0; j < 4; j++) { mrow[j] = -3e38f; lrow[j] = 0.0f; }

  for (int kc = 0; kc < ncnt; kc++) {
    const int cur = kc & 1;
    __syncthreads();   // drains stage(kc) + all reads of buf[cur^1] from iter kc-1
    if (kc + 1 < ncnt) stage(cur ^ 1, plan.idx[n][kc + 1]);

    // Q A-frags (row = wave*16 + l15, dh slice l4*8 within 32-step)
    bf16x8 qaf[2];
#pragma unroll
    for (int ks_ = 0; ks_ < 2; ks_++) {
      int r = wave * 16 + l15;
      qaf[ks_] = *(const bf16x8*)(qs + r * 64 + ((ks_ * 32 + l4 * 8) ^ ((r & 7) << 3)));
    }

    // QK^T: S[16q x 64k] per wave
    f32x4 sacc[4] = {};
#pragma unroll
    for (int nn = 0; nn < 4; nn++) {
      int r = nn * 16 + l15;
#pragma unroll
      for (int ks_ = 0; ks_ < 2; ks_++) {
        bf16x8 kf = *(const bf16x8*)(&ks[cur][r * 64 + ((ks_ * 32 + l4 * 8) ^ ((r & 7) << 3))]);
        sacc[nn] = __builtin_amdgcn_mfma_f32_16x16x32_bf16(qaf[ks_], kf, sacc[nn], 0, 0, 0);
      }
    }

    bool vld[4];
#pragma unroll
    for (int nn = 0; nn < 4; nn++) vld[nn] = km[kc * 64 + nn * 16 + l15] != 0;

    // online softmax; rows per lane: q = wave*16 + l4*4 + j (16-lane row groups)
    float p[4][4], rmax[4], alpha[4];
#pragma unroll
    for (int j = 0; j < 4; j++) {
      float mj = -3e38f;
#pragma unroll
      for (int nn = 0; nn < 4; nn++) {
        float sv = sacc[nn][j] * 0.125f;
        p[nn][j] = sv;
        if (vld[nn]) mj = fmaxf(mj, sv);
      }
      rmax[j] = mj;
    }
#pragma unroll
    for (int d = 1; d < 16; d <<= 1) {
#pragma unroll
      for (int j = 0; j < 4; j++) rmax[j] = fmaxf(rmax[j], __shfl_xor(rmax[j], d));
    }
#pragma unroll
    for (int j = 0; j < 4; j++) {
      float mn = fmaxf(mrow[j], rmax[j]);
      alpha[j] = __expf(mrow[j] - mn);
      mrow[j] = mn;
      float psum = 0.0f;
#pragma unroll
      for (int nn = 0; nn < 4; nn++) {
        float pv = vld[nn] ? __expf(p[nn][j] - mn) : 0.0f;
        p[nn][j] = pv;
        psum += pv;
      }
      lrow[j] = lrow[j] * alpha[j] + psum;
    }
#pragma unroll
    for (int n2 = 0; n2 < 4; n2++)
#pragma unroll
      for (int j = 0; j < 4; j++) oacc[n2][j] *= alpha[j];

    // P -> bf16 -> LDS (wave-private rows; same-wave in-order LDS, no barrier)
#pragma unroll
    for (int nn = 0; nn < 4; nn++)
#pragma unroll
      for (int j = 0; j < 4; j++) {
        int q = wave * 16 + l4 * 4 + j;
        ps[q * 64 + ((nn * 16 + l15) ^ ((q & 7) << 3))] = f2b(p[nn][j]);
      }

    // PV: O[16q x 64dh] += P[16x64] * V^T[64dh x 64k]^T
#pragma unroll
    for (int ks_ = 0; ks_ < 2; ks_++) {
      int r = wave * 16 + l15;
      bf16x8 paf = *(const bf16x8*)(ps + r * 64 + ((ks_ * 32 + l4 * 8) ^ ((r & 7) << 3)));
#pragma unroll
      for (int n2 = 0; n2 < 4; n2++) {
        int rv = n2 * 16 + l15;
        bf16x8 vf = *(const bf16x8*)(&vt[cur][rv * 64 + ((ks_ * 32 + l4 * 8) ^ ((rv & 7) << 3))]);
        oacc[n2] = __builtin_amdgcn_mfma_f32_16x16x32_bf16(paf, vf, oacc[n2], 0, 0, 0);
      }
    }
  }

  // reduce row sums across the 16-lane row group, normalize, store
#pragma unroll
  for (int d = 1; d < 16; d <<= 1) {
#pragma unroll
    for (int j = 0; j < 4; j++) lrow[j] += __shfl_xor(lrow[j], d);
  }
#pragma unroll
  for (int j = 0; j < 4; j++) {
    const float inv = lrow[j] > 0.0f ? 1.0f / lrow[j] : 0.0f;
    const int q = n * 64 + wave * 16 + l4 * 4 + j;
#pragma unroll
    for (int n2 = 0; n2 < 4; n2++) {
      outb[(size_t)(b * S_ + q) * D_ + h0 * 64 + n2 * 16 + l15] = f2b(oacc[n2][j] * inv);
    }
  }
}

// ---------- host-side exact numpy RandomState(MT19937) plan ----------
namespace {
struct HostMT {
  u32 mt[624]; int mti;
  void seed(u32 s) {
    mt[0] = s;
    for (int i = 1; i < 624; i++)
      mt[i] = 1812433253u * (mt[i - 1] ^ (mt[i - 1] >> 30)) + (u32)i;
    mti = 624;
  }
  u32 next() {
    if (mti >= 624) {
      for (int k = 0; k < 624; k++) {
        u32 y = (mt[k] & 0x80000000u) | (mt[(k + 1) % 624] & 0x7fffffffu);
        mt[k] = mt[(k + 397) % 624] ^ (y >> 1) ^ ((y & 1u) ? 0x9908b0dfu : 0u);
      }
      mti = 0;
    }
    u32 y = mt[mti++];
    y ^= y >> 11;
    y ^= (y << 7)  & 0x9d2c5680u;
    y ^= (y << 15) & 0xefc60000u;
    y ^= y >> 18;
    return y;
  }
  u32 interval(u32 mx) {
    if (mx == 0u) return 0u;
    u32 mask = mx;
    mask |= mask >> 1; mask |= mask >> 2; mask |= mask >> 4;
    mask |= mask >> 8; mask |= mask >> 16;
    u32 v;
    while ((v = (next() & mask)) > mx) {}
    return v;
  }
};

void build_plan(int l, Plan* out) {
  HostMT rng;
  rng.seed((u32)l);
  for (int i = 0; i < NB_; i++) {
    bool fixedv[NB_] = {};
    fixedv[0] = true; fixedv[NB_ - 1] = true;
    for (int j = i - 1; j <= i + 1; j++)
      if (j >= 0 && j < NB_) fixedv[j] = true;
    int rest[NB_]; int nr = 0;
    for (int j = 0; j < NB_; j++) if (!fixedv[j]) rest[nr++] = j;
    int perm[NB_];
    for (int tt = 0; tt < nr; tt++) perm[tt] = tt;
    for (int tt = nr - 1; tt >= 1; tt--) {
      int j = (int)rng.interval((u32)tt);
      int tmp = perm[tt]; perm[tt] = perm[j]; perm[j] = tmp;
    }
    bool sel[NB_];
    for (int j = 0; j < NB_; j++) sel[j] = fixedv[j];
    for (int c = 0; c < 3; c++) sel[rest[perm[c]]] = true;
    int cnt = 0;
    for (int j = 0; j < NB_; j++)
      if (sel[j]) out->idx[i][cnt++] = (unsigned char)j;
    out->cnt[i] = (unsigned char)cnt;
    for (int c2 = cnt; c2 < KC_; c2++) out->idx[i][c2] = 0;
  }
}
}  // namespace

// ---------- host orchestration ----------
extern "C" void kernel_launch(void* const* d_in, const int* in_sizes, int n_in,
                              void* d_out, int out_size, void* d_ws, size_t ws_size,
                              hipStream_t stream) {
  (void)in_sizes; (void)n_in; (void)out_size; (void)ws_size;

  const int*   tokens = (const int*)d_in[0];
  const float* embed  = (const float*)d_in[1];
  const float* ln1_s  = (const float*)d_in[2];
  const float* ln1_b  = (const float*)d_in[3];
  const float* wq     = (const float*)d_in[4];
  const float* wk     = (const float*)d_in[5];
  const float* wv     = (const float*)d_in[6];
  const float* wo     = (const float*)d_in[7];
  const float* ln2_s  = (const float*)d_in[8];
  const float* ln2_b  = (const float*)d_in[9];
  const float* w1     = (const float*)d_in[10];
  const float* b1     = (const float*)d_in[11];
  const float* w2     = (const float*)d_in[12];
  const float* b2     = (const float*)d_in[13];
  const float* lnf_s  = (const float*)d_in[14];
  const float* lnf_b  = (const float*)d_in[15];

  char* wp = (char*)d_ws;
  auto take = [&](size_t bytes) {
    void* p = (void*)wp;
    wp += (bytes + 255) & ~(size_t)255;
    return p;
  };

  const int Mrows = B_ * S_;
  u16* wqkvT = (u16*)take((size_t)L_ * 1536 * D_ * 2);   // [L][1536][512]
  u16* woT   = (u16*)take((size_t)L_ * D_ * D_ * 2);     // [L][512][512]
  u16* w1T   = (u16*)take((size_t)L_ * FF_ * D_ * 2);    // [L][2048][512]
  u16* w2T   = (u16*)take((size_t)L_ * D_ * FF_ * 2);    // [L][512][2048]
  float* x   = (float*)take((size_t)Mrows * D_ * 4);
  u16* h     = (u16*)take((size_t)Mrows * D_ * 2);
  u16* big   = (u16*)take((size_t)Mrows * FF_ * 2);      // {qkv(16.8M)+vT(8.4M)} | g(33.5M)
  u16* qkv   = big;                                      // [8192][1024] q|k
  u16* vT    = big + (size_t)Mrows * 1024;               // [512][8192]
  u16* g     = big;

  Plan plans[L_];
  for (int l = 0; l < L_; l++) build_plan(l, &plans[l]);

  const size_t qkvL = (size_t)1536 * D_;

  transpose_conv<<<dim3(D_ / 32, D_ / 32, L_), dim3(32, 8), 0, stream>>>(wq, wqkvT, D_, D_, qkvL, 0);
  transpose_conv<<<dim3(D_ / 32, D_ / 32, L_), dim3(32, 8), 0, stream>>>(wk, wqkvT, D_, D_, qkvL, 512);
  transpose_conv<<<dim3(D_ / 32, D_ / 32, L_), dim3(32, 8), 0, stream>>>(wv, wqkvT, D_, D_, qkvL, 1024);
  transpose_conv<<<dim3(D_ / 32, D_ / 32, L_), dim3(32, 8), 0, stream>>>(wo, woT, D_, D_, (size_t)D_ * D_, 0);
  transpose_conv<<<dim3(FF_ / 32, D_ / 32, L_), dim3(32, 8), 0, stream>>>(w1, w1T, D_, FF_, (size_t)FF_ * D_, 0);
  transpose_conv<<<dim3(D_ / 32, FF_ / 32, L_), dim3(32, 8), 0, stream>>>(w2, w2T, FF_, D_, (size_t)D_ * FF_, 0);
  embed_kernel<<<Mrows, 128, 0, stream>>>(tokens, embed, x);

  for (int l = 0; l < L_; l++) {
    ln_kernel<true><<<Mrows, 128, 0, stream>>>(x, ln1_s + l * D_, ln1_b + l * D_, h);
    gemm_bt<0, 128, true><<<dim3(Mrows / 128, 12), 256, 0, stream>>>(
        h, wqkvT + (size_t)l * qkvL, D_, 1024, nullptr, qkv, nullptr, nullptr, vT);
    attn_mfma<<<B_ * NB_ * H_, 256, 0, stream>>>(qkv, vT, tokens, h, plans[l]);
    gemm_bt<1, 64, false><<<dim3(Mrows / 128, 8), 256, 0, stream>>>(
        h, woT + (size_t)l * D_ * D_, D_, D_, x, nullptr, nullptr, x, nullptr);
    ln_kernel<true><<<Mrows, 128, 0, stream>>>(x, ln2_s + l * D_, ln2_b + l * D_, h);
    gemm_bt<2, 128, false><<<dim3(Mrows / 128, 16), 256, 0, stream>>>(
        h, w1T + (size_t)l * FF_ * D_, D_, FF_, nullptr, g, b1 + l * FF_, nullptr, nullptr);
    gemm_bt<3, 64, false><<<dim3(Mrows / 128, 8), 256, 0, stream>>>(
        g, w2T + (size_t)l * D_ * FF_, FF_, D_, x, nullptr, b2 + l * D_, x, nullptr);
  }
  ln_kernel<false><<<Mrows, 128, 0, stream>>>(x, lnf_s, lnf_b, d_out);
}

// Round 4
// 923.136 us; speedup vs baseline: 4.2873x; 1.0076x over previous
//
#include <hip/hip_runtime.h>

using u32 = unsigned int;
using u16 = unsigned short;

#define B_   4
#define S_   2048
#define D_   512
#define H_   8
#define DH_  64
#define FF_  2048
#define L_   6
#define NB_  32
#define KC_  8

typedef __attribute__((ext_vector_type(8))) __bf16 bf16x8;
typedef __attribute__((ext_vector_type(4))) float  f32x4;

struct Plan { unsigned char idx[NB_][KC_]; unsigned char cnt[NB_]; };

// Q prescale folded into QKV GEMM epilogue: 1/sqrt(64) * log2(e)  (base-2 softmax)
#define QSCALE 0.18033688011112042f

// ---------- helpers ----------
__device__ __forceinline__ u16 f2b(float f) {
  union { __bf16 b; u16 u; } x;
  x.b = (__bf16)f;            // hw v_cvt (RNE)
  return x.u;
}

// exact tanh-gelu via sigmoid identity: 0.5*(1+tanh(y)) == 1/(1+e^{-2y})
__device__ __forceinline__ float gelu_f(float x) {
  float y2 = 1.5957691216f * x + 0.0713548163f * x * x * x;  // 2*y
  return x / (1.0f + __expf(-y2));
}

// async global->LDS 16B per lane. dst = wave-uniform base; lane l lands at +l*16B.
typedef const __attribute__((address_space(1))) u32* gas_t;
typedef __attribute__((address_space(3))) u32* las_t;
__device__ __forceinline__ void glds16(const u16* g, u16* l) {
  __builtin_amdgcn_global_load_lds((gas_t)g, (las_t)l, 16, 0, 0);
}

// ---------- weight transpose-convert: in f32 [L][R][C] -> out bf16 rows=C cols=R ----------
__global__ __launch_bounds__(256)
void transpose_conv(const float* __restrict__ in, u16* __restrict__ out, int R, int C,
                    size_t lstride, int rowoff) {
  __shared__ float tile[32][33];
  const int l = blockIdx.z;
  const float* src = in + (size_t)l * R * C;
  u16* dst = out + (size_t)l * lstride;
  const int c0 = blockIdx.x * 32, r0 = blockIdx.y * 32;
  const int tx = threadIdx.x, ty = threadIdx.y;
#pragma unroll
  for (int i = 0; i < 4; i++)
    tile[ty + i * 8][tx] = src[(size_t)(r0 + ty + i * 8) * C + c0 + tx];
  __syncthreads();
#pragma unroll
  for (int i = 0; i < 4; i++)
    dst[(size_t)(rowoff + c0 + ty + i * 8) * R + r0 + tx] = f2b(tile[tx][ty + i * 8]);
}

// ---------- embedding + sinusoidal pos ----------
__global__ __launch_bounds__(128)
void embed_kernel(const int* __restrict__ tokens, const float* __restrict__ emb,
                  float* __restrict__ x) {
  const int row = blockIdx.x;           // b*S + s
  const int s = row & (S_ - 1);
  const int t = threadIdx.x;
  const int tok = tokens[row];
  float4 v = ((const float4*)(emb + (size_t)tok * D_))[t];
  float va[4] = {v.x, v.y, v.z, v.w};
  const float cc = -2.0f * logf(10000.0f) / (float)D_;
  const float pos = (float)s;
#pragma unroll
  for (int j = 0; j < 4; j++) {
    int d = t * 4 + j;
    int i = d >> 1;
    float dv = expf(cc * (float)i);
    float ang = pos * dv;
    va[j] += (d & 1) ? cosf(ang) : sinf(ang);
  }
  ((float4*)x)[(size_t)row * (D_ / 4) + t] = make_float4(va[0], va[1], va[2], va[3]);
}

// ---------- layernorm: f32 in -> bf16 (or f32) out ----------
template <bool BF16OUT>
__global__ __launch_bounds__(128)
void ln_kernel(const float* __restrict__ x, const float* __restrict__ sc,
               const float* __restrict__ bi, void* __restrict__ outp) {
  const int row = blockIdx.x;
  const int t = threadIdx.x;
  float4 v = ((const float4*)(x + (size_t)row * D_))[t];
  float va[4] = {v.x, v.y, v.z, v.w};
  float s = va[0] + va[1] + va[2] + va[3];
  float sq = va[0] * va[0] + va[1] * va[1] + va[2] * va[2] + va[3] * va[3];
#pragma unroll
  for (int d = 1; d < 64; d <<= 1) {
    s  += __shfl_xor(s, d);
    sq += __shfl_xor(sq, d);
  }
  __shared__ float red[4];
  const int wv = t >> 6, lane = t & 63;
  if (lane == 0) { red[wv * 2] = s; red[wv * 2 + 1] = sq; }
  __syncthreads();
  const float ts  = red[0] + red[2];
  const float tsq = red[1] + red[3];
  const float mean = ts * (1.0f / (float)D_);
  const float inv  = rsqrtf(tsq * (1.0f / (float)D_) - mean * mean + 1e-6f);
  const int d0 = t * 4;
  float o[4];
#pragma unroll
  for (int j = 0; j < 4; j++)
    o[j] = (va[j] - mean) * inv * sc[d0 + j] + bi[d0 + j];
  if (BF16OUT) {
    ushort4 u;
    u.x = f2b(o[0]); u.y = f2b(o[1]); u.z = f2b(o[2]); u.w = f2b(o[3]);
    ((ushort4*)outp)[(size_t)row * (D_ / 4) + t] = u;
  } else {
    ((float4*)outp)[(size_t)row * (D_ / 4) + t] = make_float4(o[0], o[1], o[2], o[3]);
  }
}

// ---------- bf16 MFMA GEMM, double-buffered BK=32, 1 barrier/iter ----------
// C[M,N] = A[M,K] * BT[N,K]^T  (+ epilogue)
// MODE 0: out bf16 (stride ostride); VSPLIT: cols>=1024 transposed to vtout[c-1024][r],
//         cols<512 (Q) scaled by QSCALE
// MODE 1: out f32 = acc + resid
// MODE 2: out bf16 = gelu(acc + bias)
// MODE 3: out f32 = acc + bias + resid
template <int MODE, int BN, bool VSPLIT>
__global__ __launch_bounds__(256)
void gemm_bt(const u16* __restrict__ A, const u16* __restrict__ BT,
             int Kk, int ostride,
             float* __restrict__ outf, u16* __restrict__ outb,
             const float* __restrict__ bias, const float* __restrict__ resid,
             u16* __restrict__ vtout) {
  constexpr int MI  = (BN == 128) ? 4 : 2;
  constexpr int BCH = BN / 64;                 // B-stage glds per wave
  __shared__ u16 As[2][128 * 32];
  __shared__ u16 Bs[2][BN * 32];
  const int tid = threadIdx.x;
  const int wave = tid >> 6, lane = tid & 63;
  const int row0 = blockIdx.x * 128, col0 = blockIdx.y * BN;
  const int wr = (BN == 128) ? (wave >> 1) : wave;
  const int wc = (BN == 128) ? (wave & 1) : 0;
  const int l15 = lane & 15, l4 = lane >> 4;

  // staging source pointers (per lane), k-slot XOR-swizzled (slot ^= (row>>1)&3)
  const u16* asrc[2];
  int adst[2];
#pragma unroll
  for (int i = 0; i < 2; i++) {
    int c0 = wave * 128 + i * 64;
    int cl = c0 + lane;
    int r = cl >> 2, s = cl & 3;
    asrc[i] = A + (size_t)(row0 + r) * Kk + ((s ^ ((r >> 1) & 3)) << 3);
    adst[i] = c0 * 8;
  }
  const u16* bsrc[BCH];
  int bdst[BCH];
#pragma unroll
  for (int i = 0; i < BCH; i++) {
    int c0 = wave * (BCH * 64) + i * 64;
    int cl = c0 + lane;
    int r = cl >> 2, s = cl & 3;
    bsrc[i] = BT + (size_t)(col0 + r) * Kk + ((s ^ ((r >> 1) & 3)) << 3);
    bdst[i] = c0 * 8;
  }

  // frag LDS offsets (u16 index); same swizzle on read side
  const int swz = (l4 ^ ((l15 >> 1) & 3)) << 3;
  int aoff[MI], boff[4];
#pragma unroll
  for (int m = 0; m < MI; m++) aoff[m] = (wr * (MI * 16) + m * 16 + l15) * 32 + swz;
#pragma unroll
  for (int n = 0; n < 4; n++)  boff[n] = (wc * 64 + n * 16 + l15) * 32 + swz;

  f32x4 acc[MI][4] = {};
  const int nk = Kk >> 5;

  // prologue: stage k-tile 0 into buf 0
#pragma unroll
  for (int i = 0; i < 2; i++) glds16(asrc[i], &As[0][adst[i]]);
#pragma unroll
  for (int i = 0; i < BCH; i++) glds16(bsrc[i], &Bs[0][bdst[i]]);

  for (int t = 0; t < nk; ++t) {
    const int cur = t & 1;
    __syncthreads();   // drains stage(t) glds + everyone's reads of buf[cur^1]
    if (t + 1 < nk) {
      const int ko = (t + 1) << 5;
#pragma unroll
      for (int i = 0; i < 2; i++) glds16(asrc[i] + ko, &As[cur ^ 1][adst[i]]);
#pragma unroll
      for (int i = 0; i < BCH; i++) glds16(bsrc[i] + ko, &Bs[cur ^ 1][bdst[i]]);
    }
    bf16x8 af[MI], bfr[4];
#pragma unroll
    for (int m = 0; m < MI; m++) af[m] = *(const bf16x8*)&As[cur][aoff[m]];
#pragma unroll
    for (int n = 0; n < 4; n++)  bfr[n] = *(const bf16x8*)&Bs[cur][boff[n]];
#pragma unroll
    for (int m = 0; m < MI; m++)
#pragma unroll
      for (int n = 0; n < 4; n++)
        acc[m][n] = __builtin_amdgcn_mfma_f32_16x16x32_bf16(af[m], bfr[n], acc[m][n], 0, 0, 0);
  }

#pragma unroll
  for (int m = 0; m < MI; m++) {
#pragma unroll
    for (int n = 0; n < 4; n++) {
      const int c = col0 + wc * 64 + n * 16 + l15;
      const int rb = row0 + wr * (MI * 16) + m * 16 + l4 * 4;
      if (VSPLIT && c >= 1024) {
        u16 pk[4];
#pragma unroll
        for (int j = 0; j < 4; j++) pk[j] = f2b(acc[m][n][j]);
        *(uint2*)(vtout + (size_t)(c - 1024) * (B_ * S_) + rb) = *(const uint2*)pk;
      } else {
#pragma unroll
        for (int j = 0; j < 4; j++) {
          const size_t o = (size_t)(rb + j) * ostride + c;
          float v = acc[m][n][j];
          if (MODE == 0) {
            if (VSPLIT && c < 512) v *= QSCALE;   // pre-scale Q for base-2 softmax
            outb[o] = f2b(v);
          } else if (MODE == 1) {
            outf[o] = v + resid[o];
          } else if (MODE == 2) {
            outb[o] = f2b(gelu_f(v + bias[c]));
          } else {
            outf[o] = v + bias[c] + resid[o];
          }
        }
      }
    }
  }
}

// ---------- MFMA block-sparse attention, K/V^T double-buffered prefetch ----------
// One wg per (b, block n, head h): 4 waves, wave w owns q rows [w*16, w*16+16).
// qkv: [B*S][1024] bf16 (q | k at col 0 | 512, head slice h*64; q pre-scaled by QSCALE).
// vT: [512][B*S] bf16. LDS row swizzle (128B rows): u16 idx = row*64 + (col ^ ((row&7)<<3)).
// Q lives in registers; token-validity prefetched to registers. LDS = 40960B -> 4 blocks/CU.
__global__ __launch_bounds__(256, 4)
void attn_mfma(const u16* __restrict__ qkv, const u16* __restrict__ vTg,
               const int* __restrict__ tokens, u16* __restrict__ outb, Plan plan) {
  __shared__ u16 ks[2][64 * 64];
  __shared__ u16 vt[2][64 * 64];
  __shared__ u16 ps[64 * 64];

  const int blk = blockIdx.x;
  const int h0 = blk & 7;
  const int n  = (blk >> 3) & 31;
  const int b  = blk >> 8;
  const int t  = threadIdx.x;
  const int wave = t >> 6, lane = t & 63;
  const int l15 = lane & 15, l4 = lane >> 4;
  const int ncnt = plan.cnt[n];
  const int qrow0 = b * S_ + n * 64;

  // K/V stage + next-block token prefetch
  auto stage = [&](int bi, int c, int* tkd) {
    const int krow0 = b * S_ + c * 64;
#pragma unroll
    for (int i = 0; i < 2; i++) {
      int c0 = i * 256 + wave * 64;
      int cl = c0 + lane;
      int r = cl >> 3, s = cl & 7;
      int sw = (s ^ (r & 7)) << 3;
      glds16(qkv + (size_t)(krow0 + r) * 1024 + 512 + h0 * 64 + sw, &ks[bi][c0 * 8]);
      glds16(vTg + (size_t)(h0 * 64 + r) * (B_ * S_) + krow0 + sw, &vt[bi][c0 * 8]);
    }
#pragma unroll
    for (int nn = 0; nn < 4; nn++) tkd[nn] = tokens[krow0 + nn * 16 + l15];
  };

  // Q A-frags straight from global (row = wave*16 + l15, dh slice ks*32 + l4*8)
  bf16x8 qaf[2];
#pragma unroll
  for (int ks_ = 0; ks_ < 2; ks_++)
    qaf[ks_] = *(const bf16x8*)(qkv + (size_t)(qrow0 + wave * 16 + l15) * 1024 +
                                h0 * 64 + ks_ * 32 + l4 * 8);

  int tk[4], tn[4];
  stage(0, plan.idx[n][0], tk);

  f32x4 oacc[4] = {};
  float mrow[4], lrow[4];
#pragma unroll
  for (int j = 0; j < 4; j++) { mrow[j] = -3e38f; lrow[j] = 0.0f; }

  for (int kc = 0; kc < ncnt; kc++) {
    const int cur = kc & 1;
    __syncthreads();   // drains stage(kc) + all reads of buf[cur^1] from iter kc-1
    if (kc + 1 < ncnt) stage(cur ^ 1, plan.idx[n][kc + 1], tn);

    // QK^T: S[16q x 64k] per wave (scores already in log2 units via Q prescale)
    f32x4 sacc[4] = {};
#pragma unroll
    for (int nn = 0; nn < 4; nn++) {
      int r = nn * 16 + l15;
#pragma unroll
      for (int ks_ = 0; ks_ < 2; ks_++) {
        bf16x8 kf = *(const bf16x8*)(&ks[cur][r * 64 + ((ks_ * 32 + l4 * 8) ^ ((r & 7) << 3))]);
        sacc[nn] = __builtin_amdgcn_mfma_f32_16x16x32_bf16(qaf[ks_], kf, sacc[nn], 0, 0, 0);
      }
    }

    bool vld[4];
#pragma unroll
    for (int nn = 0; nn < 4; nn++) vld[nn] = tk[nn] > 0;

    // online softmax (base 2); rows per lane: q = wave*16 + l4*4 + j
    float rmax[4];
#pragma unroll
    for (int j = 0; j < 4; j++) {
      float mj = -3e38f;
#pragma unroll
      for (int nn = 0; nn < 4; nn++)
        if (vld[nn]) mj = fmaxf(mj, sacc[nn][j]);
      rmax[j] = mj;
    }
#pragma unroll
    for (int d = 1; d < 16; d <<= 1) {
#pragma unroll
      for (int j = 0; j < 4; j++) rmax[j] = fmaxf(rmax[j], __shfl_xor(rmax[j], d));
    }
    int chg = 0;
#pragma unroll
    for (int j = 0; j < 4; j++) chg |= (rmax[j] > mrow[j]);
    if (__ballot(chg)) {     // wave-uniform: some row has a new max -> rescale
#pragma unroll
      for (int j = 0; j < 4; j++) {
        float mn = fmaxf(mrow[j], rmax[j]);
        float alpha = exp2f(mrow[j] - mn);
        mrow[j] = mn;
        lrow[j] *= alpha;
#pragma unroll
        for (int n2 = 0; n2 < 4; n2++) oacc[n2][j] *= alpha;
      }
    }
    float p[4][4];
#pragma unroll
    for (int j = 0; j < 4; j++) {
      float psum = 0.0f;
#pragma unroll
      for (int nn = 0; nn < 4; nn++) {
        float pv = vld[nn] ? exp2f(sacc[nn][j] - mrow[j]) : 0.0f;
        p[nn][j] = pv;
        psum += pv;
      }
      lrow[j] += psum;       // lane-partial; reduced once at the end
    }

    // P -> bf16 -> LDS (wave-private rows; same-wave in-order LDS, no barrier)
#pragma unroll
    for (int nn = 0; nn < 4; nn++)
#pragma unroll
      for (int j = 0; j < 4; j++) {
        int q = wave * 16 + l4 * 4 + j;
        ps[q * 64 + ((nn * 16 + l15) ^ ((q & 7) << 3))] = f2b(p[nn][j]);
      }

    // PV: O[16q x 64dh] += P[16x64] * V^T[64dh x 64k]^T
#pragma unroll
    for (int ks_ = 0; ks_ < 2; ks_++) {
      int r = wave * 16 + l15;
      bf16x8 paf = *(const bf16x8*)(ps + r * 64 + ((ks_ * 32 + l4 * 8) ^ ((r & 7) << 3)));
#pragma unroll
      for (int n2 = 0; n2 < 4; n2++) {
        int rv = n2 * 16 + l15;
        bf16x8 vf = *(const bf16x8*)(&vt[cur][rv * 64 + ((ks_ * 32 + l4 * 8) ^ ((rv & 7) << 3))]);
        oacc[n2] = __builtin_amdgcn_mfma_f32_16x16x32_bf16(paf, vf, oacc[n2], 0, 0, 0);
      }
    }
#pragma unroll
    for (int nn = 0; nn < 4; nn++) tk[nn] = tn[nn];
  }

  // reduce row sums across the 16-lane row group, normalize, store
#pragma unroll
  for (int d = 1; d < 16; d <<= 1) {
#pragma unroll
    for (int j = 0; j < 4; j++) lrow[j] += __shfl_xor(lrow[j], d);
  }
#pragma unroll
  for (int j = 0; j < 4; j++) {
    const float inv = lrow[j] > 0.0f ? 1.0f / lrow[j] : 0.0f;
    const int q = n * 64 + wave * 16 + l4 * 4 + j;
#pragma unroll
    for (int n2 = 0; n2 < 4; n2++) {
      outb[(size_t)(b * S_ + q) * D_ + h0 * 64 + n2 * 16 + l15] = f2b(oacc[n2][j] * inv);
    }
  }
}

// ---------- host-side exact numpy RandomState(MT19937) plan ----------
namespace {
struct HostMT {
  u32 mt[624]; int mti;
  void seed(u32 s) {
    mt[0] = s;
    for (int i = 1; i < 624; i++)
      mt[i] = 1812433253u * (mt[i - 1] ^ (mt[i - 1] >> 30)) + (u32)i;
    mti = 624;
  }
  u32 next() {
    if (mti >= 624) {
      for (int k = 0; k < 624; k++) {
        u32 y = (mt[k] & 0x80000000u) | (mt[(k + 1) % 624] & 0x7fffffffu);
        mt[k] = mt[(k + 397) % 624] ^ (y >> 1) ^ ((y & 1u) ? 0x9908b0dfu : 0u);
      }
      mti = 0;
    }
    u32 y = mt[mti++];
    y ^= y >> 11;
    y ^= (y << 7)  & 0x9d2c5680u;
    y ^= (y << 15) & 0xefc60000u;
    y ^= y >> 18;
    return y;
  }
  u32 interval(u32 mx) {
    if (mx == 0u) return 0u;
    u32 mask = mx;
    mask |= mask >> 1; mask |= mask >> 2; mask |= mask >> 4;
    mask |= mask >> 8; mask |= mask >> 16;
    u32 v;
    while ((v = (next() & mask)) > mx) {}
    return v;
  }
};

void build_plan(int l, Plan* out) {
  HostMT rng;
  rng.seed((u32)l);
  for (int i = 0; i < NB_; i++) {
    bool fixedv[NB_] = {};
    fixedv[0] = true; fixedv[NB_ - 1] = true;
    for (int j = i - 1; j <= i + 1; j++)
      if (j >= 0 && j < NB_) fixedv[j] = true;
    int rest[NB_]; int nr = 0;
    for (int j = 0; j < NB_; j++) if (!fixedv[j]) rest[nr++] = j;
    int perm[NB_];
    for (int tt = 0; tt < nr; tt++) perm[tt] = tt;
    for (int tt = nr - 1; tt >= 1; tt--) {
      int j = (int)rng.interval((u32)tt);
      int tmp = perm[tt]; perm[tt] = perm[j]; perm[j] = tmp;
    }
    bool sel[NB_];
    for (int j = 0; j < NB_; j++) sel[j] = fixedv[j];
    for (int c = 0; c < 3; c++) sel[rest[perm[c]]] = true;
    int cnt = 0;
    for (int j = 0; j < NB_; j++)
      if (sel[j]) out->idx[i][cnt++] = (unsigned char)j;
    out->cnt[i] = (unsigned char)cnt;
    for (int c2 = cnt; c2 < KC_; c2++) out->idx[i][c2] = 0;
  }
}
}  // namespace

// ---------- host orchestration ----------
extern "C" void kernel_launch(void* const* d_in, const int* in_sizes, int n_in,
                              void* d_out, int out_size, void* d_ws, size_t ws_size,
                              hipStream_t stream) {
  (void)in_sizes; (void)n_in; (void)out_size; (void)ws_size;

  const int*   tokens = (const int*)d_in[0];
  const float* embed  = (const float*)d_in[1];
  const float* ln1_s  = (const float*)d_in[2];
  const float* ln1_b  = (const float*)d_in[3];
  const float* wq     = (const float*)d_in[4];
  const float* wk     = (const float*)d_in[5];
  const float* wv     = (const float*)d_in[6];
  const float* wo     = (const float*)d_in[7];
  const float* ln2_s  = (const float*)d_in[8];
  const float* ln2_b  = (const float*)d_in[9];
  const float* w1     = (const float*)d_in[10];
  const float* b1     = (const float*)d_in[11];
  const float* w2     = (const float*)d_in[12];
  const float* b2     = (const float*)d_in[13];
  const float* lnf_s  = (const float*)d_in[14];
  const float* lnf_b  = (const float*)d_in[15];

  char* wp = (char*)d_ws;
  auto take = [&](size_t bytes) {
    void* p = (void*)wp;
    wp += (bytes + 255) & ~(size_t)255;
    return p;
  };

  const int Mrows = B_ * S_;
  u16* wqkvT = (u16*)take((size_t)L_ * 1536 * D_ * 2);   // [L][1536][512]
  u16* woT   = (u16*)take((size_t)L_ * D_ * D_ * 2);     // [L][512][512]
  u16* w1T   = (u16*)take((size_t)L_ * FF_ * D_ * 2);    // [L][2048][512]
  u16* w2T   = (u16*)take((size_t)L_ * D_ * FF_ * 2);    // [L][512][2048]
  float* x   = (float*)take((size_t)Mrows * D_ * 4);
  u16* h     = (u16*)take((size_t)Mrows * D_ * 2);
  u16* big   = (u16*)take((size_t)Mrows * FF_ * 2);      // {qkv(16.8M)+vT(8.4M)} | g(33.5M)
  u16* qkv   = big;                                      // [8192][1024] q|k
  u16* vT    = big + (size_t)Mrows * 1024;               // [512][8192]
  u16* g     = big;

  Plan plans[L_];
  for (int l = 0; l < L_; l++) build_plan(l, &plans[l]);

  const size_t qkvL = (size_t)1536 * D_;

  transpose_conv<<<dim3(D_ / 32, D_ / 32, L_), dim3(32, 8), 0, stream>>>(wq, wqkvT, D_, D_, qkvL, 0);
  transpose_conv<<<dim3(D_ / 32, D_ / 32, L_), dim3(32, 8), 0, stream>>>(wk, wqkvT, D_, D_, qkvL, 512);
  transpose_conv<<<dim3(D_ / 32, D_ / 32, L_), dim3(32, 8), 0, stream>>>(wv, wqkvT, D_, D_, qkvL, 1024);
  transpose_conv<<<dim3(D_ / 32, D_ / 32, L_), dim3(32, 8), 0, stream>>>(wo, woT, D_, D_, (size_t)D_ * D_, 0);
  transpose_conv<<<dim3(FF_ / 32, D_ / 32, L_), dim3(32, 8), 0, stream>>>(w1, w1T, D_, FF_, (size_t)FF_ * D_, 0);
  transpose_conv<<<dim3(D_ / 32, FF_ / 32, L_), dim3(32, 8), 0, stream>>>(w2, w2T, FF_, D_, (size_t)D_ * FF_, 0);
  embed_kernel<<<Mrows, 128, 0, stream>>>(tokens, embed, x);

  for (int l = 0; l < L_; l++) {
    ln_kernel<true><<<Mrows, 128, 0, stream>>>(x, ln1_s + l * D_, ln1_b + l * D_, h);
    gemm_bt<0, 128, true><<<dim3(Mrows / 128, 12), 256, 0, stream>>>(
        h, wqkvT + (size_t)l * qkvL, D_, 1024, nullptr, qkv, nullptr, nullptr, vT);
    attn_mfma<<<B_ * NB_ * H_, 256, 0, stream>>>(qkv, vT, tokens, h, plans[l]);
    gemm_bt<1, 64, false><<<dim3(Mrows / 128, 8), 256, 0, stream>>>(
        h, woT + (size_t)l * D_ * D_, D_, D_, x, nullptr, nullptr, x, nullptr);
    ln_kernel<true><<<Mrows, 128, 0, stream>>>(x, ln2_s + l * D_, ln2_b + l * D_, h);
    gemm_bt<2, 128, false><<<dim3(Mrows / 128, 16), 256, 0, stream>>>(
        h, w1T + (size_t)l * FF_ * D_, D_, FF_, nullptr, g, b1 + l * FF_, nullptr, nullptr);
    gemm_bt<3, 64, false><<<dim3(Mrows / 128, 8), 256, 0, stream>>>(
        g, w2T + (size_t)l * D_ * FF_, FF_, D_, x, nullptr, b2 + l * D_, x, nullptr);
  }
  ln_kernel<false><<<Mrows, 128, 0, stream>>>(x, lnf_s, lnf_b, d_out);
}

// Round 5
// 894.672 us; speedup vs baseline: 4.4238x; 1.0318x over previous
//
#include <hip/hip_runtime.h>

using u32 = unsigned int;
using u16 = unsigned short;

#define B_   4
#define S_   2048
#define D_   512
#define H_   8
#define DH_  64
#define FF_  2048
#define L_   6
#define NB_  32
#define KC_  8

typedef __attribute__((ext_vector_type(8))) __bf16 bf16x8;
typedef __attribute__((ext_vector_type(4))) float  f32x4;

struct Plan { unsigned char idx[NB_][KC_]; unsigned char cnt[NB_]; };

// Q prescale folded into QKV GEMM epilogue: 1/sqrt(64) * log2(e)  (base-2 softmax)
#define QSCALE 0.18033688011112042f

// ---------- helpers ----------
__device__ __forceinline__ u16 f2b(float f) {
  union { __bf16 b; u16 u; } x;
  x.b = (__bf16)f;            // hw v_cvt (RNE)
  return x.u;
}

// exact tanh-gelu via sigmoid identity: 0.5*(1+tanh(y)) == 1/(1+e^{-2y})
__device__ __forceinline__ float gelu_f(float x) {
  float y2 = 1.5957691216f * x + 0.0713548163f * x * x * x;  // 2*y
  return x / (1.0f + __expf(-y2));
}

// async global->LDS 16B per lane. dst = wave-uniform base; lane l lands at +l*16B.
typedef const __attribute__((address_space(1))) u32* gas_t;
typedef __attribute__((address_space(3))) u32* las_t;
__device__ __forceinline__ void glds16(const u16* g, u16* l) {
  __builtin_amdgcn_global_load_lds((gas_t)g, (las_t)l, 16, 0, 0);
}

// ---------- weight transpose-convert: in f32 [L][R][C] -> out bf16 rows=C cols=R ----------
__global__ __launch_bounds__(256)
void transpose_conv(const float* __restrict__ in, u16* __restrict__ out, int R, int C,
                    size_t lstride, int rowoff) {
  __shared__ float tile[32][33];
  const int l = blockIdx.z;
  const float* src = in + (size_t)l * R * C;
  u16* dst = out + (size_t)l * lstride;
  const int c0 = blockIdx.x * 32, r0 = blockIdx.y * 32;
  const int tx = threadIdx.x, ty = threadIdx.y;
#pragma unroll
  for (int i = 0; i < 4; i++)
    tile[ty + i * 8][tx] = src[(size_t)(r0 + ty + i * 8) * C + c0 + tx];
  __syncthreads();
#pragma unroll
  for (int i = 0; i < 4; i++)
    dst[(size_t)(rowoff + c0 + ty + i * 8) * R + r0 + tx] = f2b(tile[tx][ty + i * 8]);
}

// ---------- embedding + sinusoidal pos ----------
__global__ __launch_bounds__(128)
void embed_kernel(const int* __restrict__ tokens, const float* __restrict__ emb,
                  float* __restrict__ x) {
  const int row = blockIdx.x;           // b*S + s
  const int s = row & (S_ - 1);
  const int t = threadIdx.x;
  const int tok = tokens[row];
  float4 v = ((const float4*)(emb + (size_t)tok * D_))[t];
  float va[4] = {v.x, v.y, v.z, v.w};
  const float cc = -2.0f * logf(10000.0f) / (float)D_;
  const float pos = (float)s;
#pragma unroll
  for (int j = 0; j < 4; j++) {
    int d = t * 4 + j;
    int i = d >> 1;
    float dv = expf(cc * (float)i);
    float ang = pos * dv;
    va[j] += (d & 1) ? cosf(ang) : sinf(ang);
  }
  ((float4*)x)[(size_t)row * (D_ / 4) + t] = make_float4(va[0], va[1], va[2], va[3]);
}

// ---------- layernorm: f32 in -> bf16 (or f32) out ----------
template <bool BF16OUT>
__global__ __launch_bounds__(128)
void ln_kernel(const float* __restrict__ x, const float* __restrict__ sc,
               const float* __restrict__ bi, void* __restrict__ outp) {
  const int row = blockIdx.x;
  const int t = threadIdx.x;
  float4 v = ((const float4*)(x + (size_t)row * D_))[t];
  float va[4] = {v.x, v.y, v.z, v.w};
  float s = va[0] + va[1] + va[2] + va[3];
  float sq = va[0] * va[0] + va[1] * va[1] + va[2] * va[2] + va[3] * va[3];
#pragma unroll
  for (int d = 1; d < 64; d <<= 1) {
    s  += __shfl_xor(s, d);
    sq += __shfl_xor(sq, d);
  }
  __shared__ float red[4];
  const int wv = t >> 6, lane = t & 63;
  if (lane == 0) { red[wv * 2] = s; red[wv * 2 + 1] = sq; }
  __syncthreads();
  const float ts  = red[0] + red[2];
  const float tsq = red[1] + red[3];
  const float mean = ts * (1.0f / (float)D_);
  const float inv  = rsqrtf(tsq * (1.0f / (float)D_) - mean * mean + 1e-6f);
  const int d0 = t * 4;
  float o[4];
#pragma unroll
  for (int j = 0; j < 4; j++)
    o[j] = (va[j] - mean) * inv * sc[d0 + j] + bi[d0 + j];
  if (BF16OUT) {
    ushort4 u;
    u.x = f2b(o[0]); u.y = f2b(o[1]); u.z = f2b(o[2]); u.w = f2b(o[3]);
    ((ushort4*)outp)[(size_t)row * (D_ / 4) + t] = u;
  } else {
    ((float4*)outp)[(size_t)row * (D_ / 4) + t] = make_float4(o[0], o[1], o[2], o[3]);
  }
}

// ---------- 256x256 BK=64 GEMM, counted-vmcnt pipeline (T2+T3+T4+T5) ----------
// C[M,N] = A[M,K] * BT[N,K]^T. 8 waves (2Mx4N), per-wave 128x64 out.
// LDS 128KiB: As/Bs [2][256*64] u16, row stride 64 u16 = 128B.
// Slot swizzle (16B slots, 8/row): lds slot = gslot ^ (row&7); glds uses
// pre-swizzled global source + linear LDS dst (rule 21 both-sides).
// Loop: vmcnt(8) -> B1 -> ds_read ks0 -> MFMA ks0 -> ds_read ks1 ->
//       lgkmcnt(0) -> B2 -> stage(kt+2) -> setprio(1) MFMA ks1 setprio(0)
template <int MODE, bool VSPLIT>
__global__ __launch_bounds__(512)
void gemm256(const u16* __restrict__ A, const u16* __restrict__ BT,
             int Kk, int ostride,
             float* __restrict__ outf, u16* __restrict__ outb,
             const float* __restrict__ bias, const float* __restrict__ resid,
             u16* __restrict__ vtout) {
  __shared__ u16 As[2][256 * 64];
  __shared__ u16 Bs[2][256 * 64];
  const int tid = threadIdx.x;
  const int wave = tid >> 6, lane = tid & 63;
  const int row0 = blockIdx.x * 256, col0 = blockIdx.y * 256;
  const int wr = wave >> 2, wc = wave & 3;
  const int l15 = lane & 15, l4 = lane >> 4;

  // staging sources: per wave 4 A-chunks + 4 B-chunks (64 lanes x 16B each)
  const u16* asrc[4];
  const u16* bsrc[4];
  int cdst[4];
#pragma unroll
  for (int i = 0; i < 4; i++) {
    int chunk = wave * 256 + i * 64 + lane;       // 0..2047
    int r = chunk >> 3, s = chunk & 7;
    int ss = (s ^ (r & 7)) << 3;                  // pre-swizzled k-slot (u16)
    asrc[i] = A  + (size_t)(row0 + r) * Kk + ss;
    bsrc[i] = BT + (size_t)(col0 + r) * Kk + ss;
    cdst[i] = (wave * 256 + i * 64) * 8;          // wave-uniform chunk base (u16)
  }

  // frag read offsets; rA&7 == l15&7 for all m (multiples of 8 elsewhere)
  int aoff[8], boff[4];
#pragma unroll
  for (int m = 0; m < 8; m++) aoff[m] = (wr * 128 + m * 16 + l15) * 64;
#pragma unroll
  for (int n = 0; n < 4; n++) boff[n] = (wc * 64 + n * 16 + l15) * 64;
  const int sk0 = ((l4)     ^ (l15 & 7)) << 3;    // ks=0: slot l4
  const int sk1 = ((4 + l4) ^ (l15 & 7)) << 3;    // ks=1: slot 4+l4

  f32x4 acc[8][4] = {};
  const int nk = Kk >> 6;

  auto stage = [&](int buf, int kt) {
    const int ko = kt << 6;
#pragma unroll
    for (int i = 0; i < 4; i++) glds16(asrc[i] + ko, &As[buf][cdst[i]]);
#pragma unroll
    for (int i = 0; i < 4; i++) glds16(bsrc[i] + ko, &Bs[buf][cdst[i]]);
  };

  stage(0, 0);
  stage(1, 1);

  for (int kt = 0; kt < nk; ++kt) {
    const int cur = kt & 1;
    if (kt + 1 < nk) { asm volatile("s_waitcnt vmcnt(8)" ::: "memory"); }
    else             { asm volatile("s_waitcnt vmcnt(0)" ::: "memory"); }
    __builtin_amdgcn_s_barrier();                 // B1: buf[cur] staged everywhere
    __builtin_amdgcn_sched_barrier(0);

    bf16x8 af0[8], bf0[4];
#pragma unroll
    for (int m = 0; m < 8; m++) af0[m] = *(const bf16x8*)&As[cur][aoff[m] + sk0];
#pragma unroll
    for (int n = 0; n < 4; n++) bf0[n] = *(const bf16x8*)&Bs[cur][boff[n] + sk0];
#pragma unroll
    for (int m = 0; m < 8; m++)
#pragma unroll
      for (int n = 0; n < 4; n++)
        acc[m][n] = __builtin_amdgcn_mfma_f32_16x16x32_bf16(af0[m], bf0[n], acc[m][n], 0, 0, 0);

    bf16x8 af1[8], bf1[4];
#pragma unroll
    for (int m = 0; m < 8; m++) af1[m] = *(const bf16x8*)&As[cur][aoff[m] + sk1];
#pragma unroll
    for (int n = 0; n < 4; n++) bf1[n] = *(const bf16x8*)&Bs[cur][boff[n] + sk1];
    asm volatile("s_waitcnt lgkmcnt(0)" ::: "memory");
    __builtin_amdgcn_sched_barrier(0);
    __builtin_amdgcn_s_barrier();                 // B2: all reads of buf[cur] done
    __builtin_amdgcn_sched_barrier(0);
    if (kt + 2 < nk) stage(cur, kt + 2);          // overwrite buf[cur], 2 iters of flight

    __builtin_amdgcn_s_setprio(1);
#pragma unroll
    for (int m = 0; m < 8; m++)
#pragma unroll
      for (int n = 0; n < 4; n++)
        acc[m][n] = __builtin_amdgcn_mfma_f32_16x16x32_bf16(af1[m], bf1[n], acc[m][n], 0, 0, 0);
    __builtin_amdgcn_s_setprio(0);
  }

#pragma unroll
  for (int m = 0; m < 8; m++) {
#pragma unroll
    for (int n = 0; n < 4; n++) {
      const int c = col0 + wc * 64 + n * 16 + l15;
      const int rb = row0 + wr * 128 + m * 16 + l4 * 4;
      if (VSPLIT && c >= 1024) {
        u16 pk[4];
#pragma unroll
        for (int j = 0; j < 4; j++) pk[j] = f2b(acc[m][n][j]);
        *(uint2*)(vtout + (size_t)(c - 1024) * (B_ * S_) + rb) = *(const uint2*)pk;
      } else {
#pragma unroll
        for (int j = 0; j < 4; j++) {
          const size_t o = (size_t)(rb + j) * ostride + c;
          float v = acc[m][n][j];
          if (MODE == 0) {
            if (VSPLIT && c < 512) v *= QSCALE;   // pre-scale Q for base-2 softmax
            outb[o] = f2b(v);
          } else if (MODE == 1) {
            outf[o] = v + resid[o];
          } else if (MODE == 2) {
            outb[o] = f2b(gelu_f(v + bias[c]));
          } else {
            outf[o] = v + bias[c] + resid[o];
          }
        }
      }
    }
  }
}

// ---------- bf16 MFMA GEMM, double-buffered BK=32, 1 barrier/iter (small-N path) ----------
template <int MODE, int BN, bool VSPLIT>
__global__ __launch_bounds__(256)
void gemm_bt(const u16* __restrict__ A, const u16* __restrict__ BT,
             int Kk, int ostride,
             float* __restrict__ outf, u16* __restrict__ outb,
             const float* __restrict__ bias, const float* __restrict__ resid,
             u16* __restrict__ vtout) {
  constexpr int MI  = (BN == 128) ? 4 : 2;
  constexpr int BCH = BN / 64;                 // B-stage glds per wave
  __shared__ u16 As[2][128 * 32];
  __shared__ u16 Bs[2][BN * 32];
  const int tid = threadIdx.x;
  const int wave = tid >> 6, lane = tid & 63;
  const int row0 = blockIdx.x * 128, col0 = blockIdx.y * BN;
  const int wr = (BN == 128) ? (wave >> 1) : wave;
  const int wc = (BN == 128) ? (wave & 1) : 0;
  const int l15 = lane & 15, l4 = lane >> 4;

  const u16* asrc[2];
  int adst[2];
#pragma unroll
  for (int i = 0; i < 2; i++) {
    int c0 = wave * 128 + i * 64;
    int cl = c0 + lane;
    int r = cl >> 2, s = cl & 3;
    asrc[i] = A + (size_t)(row0 + r) * Kk + ((s ^ ((r >> 1) & 3)) << 3);
    adst[i] = c0 * 8;
  }
  const u16* bsrc[BCH];
  int bdst[BCH];
#pragma unroll
  for (int i = 0; i < BCH; i++) {
    int c0 = wave * (BCH * 64) + i * 64;
    int cl = c0 + lane;
    int r = cl >> 2, s = cl & 3;
    bsrc[i] = BT + (size_t)(col0 + r) * Kk + ((s ^ ((r >> 1) & 3)) << 3);
    bdst[i] = c0 * 8;
  }

  const int swz = (l4 ^ ((l15 >> 1) & 3)) << 3;
  int aoff[MI], boff[4];
#pragma unroll
  for (int m = 0; m < MI; m++) aoff[m] = (wr * (MI * 16) + m * 16 + l15) * 32 + swz;
#pragma unroll
  for (int n = 0; n < 4; n++)  boff[n] = (wc * 64 + n * 16 + l15) * 32 + swz;

  f32x4 acc[MI][4] = {};
  const int nk = Kk >> 5;

#pragma unroll
  for (int i = 0; i < 2; i++) glds16(asrc[i], &As[0][adst[i]]);
#pragma unroll
  for (int i = 0; i < BCH; i++) glds16(bsrc[i], &Bs[0][bdst[i]]);

  for (int t = 0; t < nk; ++t) {
    const int cur = t & 1;
    __syncthreads();   // drains stage(t) glds + everyone's reads of buf[cur^1]
    if (t + 1 < nk) {
      const int ko = (t + 1) << 5;
#pragma unroll
      for (int i = 0; i < 2; i++) glds16(asrc[i] + ko, &As[cur ^ 1][adst[i]]);
#pragma unroll
      for (int i = 0; i < BCH; i++) glds16(bsrc[i] + ko, &Bs[cur ^ 1][bdst[i]]);
    }
    bf16x8 af[MI], bfr[4];
#pragma unroll
    for (int m = 0; m < MI; m++) af[m] = *(const bf16x8*)&As[cur][aoff[m]];
#pragma unroll
    for (int n = 0; n < 4; n++)  bfr[n] = *(const bf16x8*)&Bs[cur][boff[n]];
#pragma unroll
    for (int m = 0; m < MI; m++)
#pragma unroll
      for (int n = 0; n < 4; n++)
        acc[m][n] = __builtin_amdgcn_mfma_f32_16x16x32_bf16(af[m], bfr[n], acc[m][n], 0, 0, 0);
  }

#pragma unroll
  for (int m = 0; m < MI; m++) {
#pragma unroll
    for (int n = 0; n < 4; n++) {
      const int c = col0 + wc * 64 + n * 16 + l15;
      const int rb = row0 + wr * (MI * 16) + m * 16 + l4 * 4;
      if (VSPLIT && c >= 1024) {
        u16 pk[4];
#pragma unroll
        for (int j = 0; j < 4; j++) pk[j] = f2b(acc[m][n][j]);
        *(uint2*)(vtout + (size_t)(c - 1024) * (B_ * S_) + rb) = *(const uint2*)pk;
      } else {
#pragma unroll
        for (int j = 0; j < 4; j++) {
          const size_t o = (size_t)(rb + j) * ostride + c;
          float v = acc[m][n][j];
          if (MODE == 0) {
            if (VSPLIT && c < 512) v *= QSCALE;
            outb[o] = f2b(v);
          } else if (MODE == 1) {
            outf[o] = v + resid[o];
          } else if (MODE == 2) {
            outb[o] = f2b(gelu_f(v + bias[c]));
          } else {
            outf[o] = v + bias[c] + resid[o];
          }
        }
      }
    }
  }
}

// ---------- MFMA block-sparse attention, K/V^T double-buffered prefetch ----------
__global__ __launch_bounds__(256, 4)
void attn_mfma(const u16* __restrict__ qkv, const u16* __restrict__ vTg,
               const int* __restrict__ tokens, u16* __restrict__ outb, Plan plan) {
  __shared__ u16 ks[2][64 * 64];
  __shared__ u16 vt[2][64 * 64];
  __shared__ u16 ps[64 * 64];

  const int blk = blockIdx.x;
  const int h0 = blk & 7;
  const int n  = (blk >> 3) & 31;
  const int b  = blk >> 8;
  const int t  = threadIdx.x;
  const int wave = t >> 6, lane = t & 63;
  const int l15 = lane & 15, l4 = lane >> 4;
  const int ncnt = plan.cnt[n];
  const int qrow0 = b * S_ + n * 64;

  auto stage = [&](int bi, int c, int* tkd) {
    const int krow0 = b * S_ + c * 64;
#pragma unroll
    for (int i = 0; i < 2; i++) {
      int c0 = i * 256 + wave * 64;
      int cl = c0 + lane;
      int r = cl >> 3, s = cl & 7;
      int sw = (s ^ (r & 7)) << 3;
      glds16(qkv + (size_t)(krow0 + r) * 1024 + 512 + h0 * 64 + sw, &ks[bi][c0 * 8]);
      glds16(vTg + (size_t)(h0 * 64 + r) * (B_ * S_) + krow0 + sw, &vt[bi][c0 * 8]);
    }
#pragma unroll
    for (int nn = 0; nn < 4; nn++) tkd[nn] = tokens[krow0 + nn * 16 + l15];
  };

  bf16x8 qaf[2];
#pragma unroll
  for (int ks_ = 0; ks_ < 2; ks_++)
    qaf[ks_] = *(const bf16x8*)(qkv + (size_t)(qrow0 + wave * 16 + l15) * 1024 +
                                h0 * 64 + ks_ * 32 + l4 * 8);

  int tk[4], tn[4];
  stage(0, plan.idx[n][0], tk);

  f32x4 oacc[4] = {};
  float mrow[4], lrow[4];
#pragma unroll
  for (int j = 0; j < 4; j++) { mrow[j] = -3e38f; lrow[j] = 0.0f; }

  for (int kc = 0; kc < ncnt; kc++) {
    const int cur = kc & 1;
    __syncthreads();
    if (kc + 1 < ncnt) stage(cur ^ 1, plan.idx[n][kc + 1], tn);

    f32x4 sacc[4] = {};
#pragma unroll
    for (int nn = 0; nn < 4; nn++) {
      int r = nn * 16 + l15;
#pragma unroll
      for (int ks_ = 0; ks_ < 2; ks_++) {
        bf16x8 kf = *(const bf16x8*)(&ks[cur][r * 64 + ((ks_ * 32 + l4 * 8) ^ ((r & 7) << 3))]);
        sacc[nn] = __builtin_amdgcn_mfma_f32_16x16x32_bf16(qaf[ks_], kf, sacc[nn], 0, 0, 0);
      }
    }

    bool vld[4];
#pragma unroll
    for (int nn = 0; nn < 4; nn++) vld[nn] = tk[nn] > 0;

    float rmax[4];
#pragma unroll
    for (int j = 0; j < 4; j++) {
      float mj = -3e38f;
#pragma unroll
      for (int nn = 0; nn < 4; nn++)
        if (vld[nn]) mj = fmaxf(mj, sacc[nn][j]);
      rmax[j] = mj;
    }
#pragma unroll
    for (int d = 1; d < 16; d <<= 1) {
#pragma unroll
      for (int j = 0; j < 4; j++) rmax[j] = fmaxf(rmax[j], __shfl_xor(rmax[j], d));
    }
    int chg = 0;
#pragma unroll
    for (int j = 0; j < 4; j++) chg |= (rmax[j] > mrow[j]);
    if (__ballot(chg)) {
#pragma unroll
      for (int j = 0; j < 4; j++) {
        float mn = fmaxf(mrow[j], rmax[j]);
        float alpha = exp2f(mrow[j] - mn);
        mrow[j] = mn;
        lrow[j] *= alpha;
#pragma unroll
        for (int n2 = 0; n2 < 4; n2++) oacc[n2][j] *= alpha;
      }
    }
    float p[4][4];
#pragma unroll
    for (int j = 0; j < 4; j++) {
      float psum = 0.0f;
#pragma unroll
      for (int nn = 0; nn < 4; nn++) {
        float pv = vld[nn] ? exp2f(sacc[nn][j] - mrow[j]) : 0.0f;
        p[nn][j] = pv;
        psum += pv;
      }
      lrow[j] += psum;
    }

#pragma unroll
    for (int nn = 0; nn < 4; nn++)
#pragma unroll
      for (int j = 0; j < 4; j++) {
        int q = wave * 16 + l4 * 4 + j;
        ps[q * 64 + ((nn * 16 + l15) ^ ((q & 7) << 3))] = f2b(p[nn][j]);
      }

#pragma unroll
    for (int ks_ = 0; ks_ < 2; ks_++) {
      int r = wave * 16 + l15;
      bf16x8 paf = *(const bf16x8*)(ps + r * 64 + ((ks_ * 32 + l4 * 8) ^ ((r & 7) << 3)));
#pragma unroll
      for (int n2 = 0; n2 < 4; n2++) {
        int rv = n2 * 16 + l15;
        bf16x8 vf = *(const bf16x8*)(&vt[cur][rv * 64 + ((ks_ * 32 + l4 * 8) ^ ((rv & 7) << 3))]);
        oacc[n2] = __builtin_amdgcn_mfma_f32_16x16x32_bf16(paf, vf, oacc[n2], 0, 0, 0);
      }
    }
#pragma unroll
    for (int nn = 0; nn < 4; nn++) tk[nn] = tn[nn];
  }

#pragma unroll
  for (int d = 1; d < 16; d <<= 1) {
#pragma unroll
    for (int j = 0; j < 4; j++) lrow[j] += __shfl_xor(lrow[j], d);
  }
#pragma unroll
  for (int j = 0; j < 4; j++) {
    const float inv = lrow[j] > 0.0f ? 1.0f / lrow[j] : 0.0f;
    const int q = n * 64 + wave * 16 + l4 * 4 + j;
#pragma unroll
    for (int n2 = 0; n2 < 4; n2++) {
      outb[(size_t)(b * S_ + q) * D_ + h0 * 64 + n2 * 16 + l15] = f2b(oacc[n2][j] * inv);
    }
  }
}

// ---------- host-side exact numpy RandomState(MT19937) plan ----------
namespace {
struct HostMT {
  u32 mt[624]; int mti;
  void seed(u32 s) {
    mt[0] = s;
    for (int i = 1; i < 624; i++)
      mt[i] = 1812433253u * (mt[i - 1] ^ (mt[i - 1] >> 30)) + (u32)i;
    mti = 624;
  }
  u32 next() {
    if (mti >= 624) {
      for (int k = 0; k < 624; k++) {
        u32 y = (mt[k] & 0x80000000u) | (mt[(k + 1) % 624] & 0x7fffffffu);
        mt[k] = mt[(k + 397) % 624] ^ (y >> 1) ^ ((y & 1u) ? 0x9908b0dfu : 0u);
      }
      mti = 0;
    }
    u32 y = mt[mti++];
    y ^= y >> 11;
    y ^= (y << 7)  & 0x9d2c5680u;
    y ^= (y << 15) & 0xefc60000u;
    y ^= y >> 18;
    return y;
  }
  u32 interval(u32 mx) {
    if (mx == 0u) return 0u;
    u32 mask = mx;
    mask |= mask >> 1; mask |= mask >> 2; mask |= mask >> 4;
    mask |= mask >> 8; mask |= mask >> 16;
    u32 v;
    while ((v = (next() & mask)) > mx) {}
    return v;
  }
};

void build_plan(int l, Plan* out) {
  HostMT rng;
  rng.seed((u32)l);
  for (int i = 0; i < NB_; i++) {
    bool fixedv[NB_] = {};
    fixedv[0] = true; fixedv[NB_ - 1] = true;
    for (int j = i - 1; j <= i + 1; j++)
      if (j >= 0 && j < NB_) fixedv[j] = true;
    int rest[NB_]; int nr = 0;
    for (int j = 0; j < NB_; j++) if (!fixedv[j]) rest[nr++] = j;
    int perm[NB_];
    for (int tt = 0; tt < nr; tt++) perm[tt] = tt;
    for (int tt = nr - 1; tt >= 1; tt--) {
      int j = (int)rng.interval((u32)tt);
      int tmp = perm[tt]; perm[tt] = perm[j]; perm[j] = tmp;
    }
    bool sel[NB_];
    for (int j = 0; j < NB_; j++) sel[j] = fixedv[j];
    for (int c = 0; c < 3; c++) sel[rest[perm[c]]] = true;
    int cnt = 0;
    for (int j = 0; j < NB_; j++)
      if (sel[j]) out->idx[i][cnt++] = (unsigned char)j;
    out->cnt[i] = (unsigned char)cnt;
    for (int c2 = cnt; c2 < KC_; c2++) out->idx[i][c2] = 0;
  }
}
}  // namespace

// ---------- host orchestration ----------
extern "C" void kernel_launch(void* const* d_in, const int* in_sizes, int n_in,
                              void* d_out, int out_size, void* d_ws, size_t ws_size,
                              hipStream_t stream) {
  (void)in_sizes; (void)n_in; (void)out_size; (void)ws_size;

  const int*   tokens = (const int*)d_in[0];
  const float* embed  = (const float*)d_in[1];
  const float* ln1_s  = (const float*)d_in[2];
  const float* ln1_b  = (const float*)d_in[3];
  const float* wq     = (const float*)d_in[4];
  const float* wk     = (const float*)d_in[5];
  const float* wv     = (const float*)d_in[6];
  const float* wo     = (const float*)d_in[7];
  const float* ln2_s  = (const float*)d_in[8];
  const float* ln2_b  = (const float*)d_in[9];
  const float* w1     = (const float*)d_in[10];
  const float* b1     = (const float*)d_in[11];
  const float* w2     = (const float*)d_in[12];
  const float* b2     = (const float*)d_in[13];
  const float* lnf_s  = (const float*)d_in[14];
  const float* lnf_b  = (const float*)d_in[15];

  char* wp = (char*)d_ws;
  auto take = [&](size_t bytes) {
    void* p = (void*)wp;
    wp += (bytes + 255) & ~(size_t)255;
    return p;
  };

  const int Mrows = B_ * S_;
  u16* wqkvT = (u16*)take((size_t)L_ * 1536 * D_ * 2);   // [L][1536][512]
  u16* woT   = (u16*)take((size_t)L_ * D_ * D_ * 2);     // [L][512][512]
  u16* w1T   = (u16*)take((size_t)L_ * FF_ * D_ * 2);    // [L][2048][512]
  u16* w2T   = (u16*)take((size_t)L_ * D_ * FF_ * 2);    // [L][512][2048]
  float* x   = (float*)take((size_t)Mrows * D_ * 4);
  u16* h     = (u16*)take((size_t)Mrows * D_ * 2);
  u16* big   = (u16*)take((size_t)Mrows * FF_ * 2);      // {qkv+vT} | g, time-shared
  u16* qkv   = big;                                      // [8192][1024] q|k
  u16* vT    = big + (size_t)Mrows * 1024;               // [512][8192]
  u16* g     = big;

  Plan plans[L_];
  for (int l = 0; l < L_; l++) build_plan(l, &plans[l]);

  const size_t qkvL = (size_t)1536 * D_;

  transpose_conv<<<dim3(D_ / 32, D_ / 32, L_), dim3(32, 8), 0, stream>>>(wq, wqkvT, D_, D_, qkvL, 0);
  transpose_conv<<<dim3(D_ / 32, D_ / 32, L_), dim3(32, 8), 0, stream>>>(wk, wqkvT, D_, D_, qkvL, 512);
  transpose_conv<<<dim3(D_ / 32, D_ / 32, L_), dim3(32, 8), 0, stream>>>(wv, wqkvT, D_, D_, qkvL, 1024);
  transpose_conv<<<dim3(D_ / 32, D_ / 32, L_), dim3(32, 8), 0, stream>>>(wo, woT, D_, D_, (size_t)D_ * D_, 0);
  transpose_conv<<<dim3(FF_ / 32, D_ / 32, L_), dim3(32, 8), 0, stream>>>(w1, w1T, D_, FF_, (size_t)FF_ * D_, 0);
  transpose_conv<<<dim3(D_ / 32, FF_ / 32, L_), dim3(32, 8), 0, stream>>>(w2, w2T, FF_, D_, (size_t)D_ * FF_, 0);
  embed_kernel<<<Mrows, 128, 0, stream>>>(tokens, embed, x);

  for (int l = 0; l < L_; l++) {
    ln_kernel<true><<<Mrows, 128, 0, stream>>>(x, ln1_s + l * D_, ln1_b + l * D_, h);
    gemm256<0, true><<<dim3(Mrows / 256, 6), 512, 0, stream>>>(
        h, wqkvT + (size_t)l * qkvL, D_, 1024, nullptr, qkv, nullptr, nullptr, vT);
    attn_mfma<<<B_ * NB_ * H_, 256, 0, stream>>>(qkv, vT, tokens, h, plans[l]);
    gemm_bt<1, 64, false><<<dim3(Mrows / 128, 8), 256, 0, stream>>>(
        h, woT + (size_t)l * D_ * D_, D_, D_, x, nullptr, nullptr, x, nullptr);
    ln_kernel<true><<<Mrows, 128, 0, stream>>>(x, ln2_s + l * D_, ln2_b + l * D_, h);
    gemm256<2, false><<<dim3(Mrows / 256, 8), 512, 0, stream>>>(
        h, w1T + (size_t)l * FF_ * D_, D_, FF_, nullptr, g, b1 + l * FF_, nullptr, nullptr);
    gemm_bt<3, 64, false><<<dim3(Mrows / 128, 8), 256, 0, stream>>>(
        g, w2T + (size_t)l * D_ * FF_, FF_, D_, x, nullptr, b2 + l * D_, x, nullptr);
  }
  ln_kernel<false><<<Mrows, 128, 0, stream>>>(x, lnf_s, lnf_b, d_out);
}

// Round 6
// 878.188 us; speedup vs baseline: 4.5068x; 1.0188x over previous
//
#include <hip/hip_runtime.h>

using u32 = unsigned int;
using u16 = unsigned short;

#define B_   4
#define S_   2048
#define D_   512
#define H_   8
#define DH_  64
#define FF_  2048
#define L_   6
#define NB_  32
#define KC_  8

typedef __attribute__((ext_vector_type(8))) __bf16 bf16x8;
typedef __attribute__((ext_vector_type(4))) float  f32x4;

struct Plan { unsigned char idx[NB_][KC_]; unsigned char cnt[NB_]; };

// Q prescale folded into QKV GEMM epilogue: 1/sqrt(64) * log2(e)  (base-2 softmax)
#define QSCALE 0.18033688011112042f

// ---------- helpers ----------
__device__ __forceinline__ u16 f2b(float f) {
  union { __bf16 b; u16 u; } x;
  x.b = (__bf16)f;            // hw v_cvt (RNE)
  return x.u;
}

// exact tanh-gelu via sigmoid identity: 0.5*(1+tanh(y)) == 1/(1+e^{-2y})
__device__ __forceinline__ float gelu_f(float x) {
  float y2 = 1.5957691216f * x + 0.0713548163f * x * x * x;  // 2*y
  return x / (1.0f + __expf(-y2));
}

// async global->LDS 16B per lane. dst = wave-uniform base; lane l lands at +l*16B.
typedef const __attribute__((address_space(1))) u32* gas_t;
typedef __attribute__((address_space(3))) u32* las_t;
__device__ __forceinline__ void glds16(const u16* g, u16* l) {
  __builtin_amdgcn_global_load_lds((gas_t)g, (las_t)l, 16, 0, 0);
}

// ---------- weight transpose-convert: in f32 [L][R][C] -> out bf16 rows=C cols=R ----------
__global__ __launch_bounds__(256)
void transpose_conv(const float* __restrict__ in, u16* __restrict__ out, int R, int C,
                    size_t lstride, int rowoff) {
  __shared__ float tile[32][33];
  const int l = blockIdx.z;
  const float* src = in + (size_t)l * R * C;
  u16* dst = out + (size_t)l * lstride;
  const int c0 = blockIdx.x * 32, r0 = blockIdx.y * 32;
  const int tx = threadIdx.x, ty = threadIdx.y;
#pragma unroll
  for (int i = 0; i < 4; i++)
    tile[ty + i * 8][tx] = src[(size_t)(r0 + ty + i * 8) * C + c0 + tx];
  __syncthreads();
#pragma unroll
  for (int i = 0; i < 4; i++)
    dst[(size_t)(rowoff + c0 + ty + i * 8) * R + r0 + tx] = f2b(tile[tx][ty + i * 8]);
}

// ---------- embedding + sinusoidal pos ----------
__global__ __launch_bounds__(128)
void embed_kernel(const int* __restrict__ tokens, const float* __restrict__ emb,
                  float* __restrict__ x) {
  const int row = blockIdx.x;           // b*S + s
  const int s = row & (S_ - 1);
  const int t = threadIdx.x;
  const int tok = tokens[row];
  float4 v = ((const float4*)(emb + (size_t)tok * D_))[t];
  float va[4] = {v.x, v.y, v.z, v.w};
  const float cc = -2.0f * logf(10000.0f) / (float)D_;
  const float pos = (float)s;
#pragma unroll
  for (int j = 0; j < 4; j++) {
    int d = t * 4 + j;
    int i = d >> 1;
    float dv = expf(cc * (float)i);
    float ang = pos * dv;
    va[j] += (d & 1) ? cosf(ang) : sinf(ang);
  }
  ((float4*)x)[(size_t)row * (D_ / 4) + t] = make_float4(va[0], va[1], va[2], va[3]);
}

// ---------- layernorm: f32 in -> bf16 (or f32) out ----------
template <bool BF16OUT>
__global__ __launch_bounds__(128)
void ln_kernel(const float* __restrict__ x, const float* __restrict__ sc,
               const float* __restrict__ bi, void* __restrict__ outp) {
  const int row = blockIdx.x;
  const int t = threadIdx.x;
  float4 v = ((const float4*)(x + (size_t)row * D_))[t];
  float va[4] = {v.x, v.y, v.z, v.w};
  float s = va[0] + va[1] + va[2] + va[3];
  float sq = va[0] * va[0] + va[1] * va[1] + va[2] * va[2] + va[3] * va[3];
#pragma unroll
  for (int d = 1; d < 64; d <<= 1) {
    s  += __shfl_xor(s, d);
    sq += __shfl_xor(sq, d);
  }
  __shared__ float red[4];
  const int wv = t >> 6, lane = t & 63;
  if (lane == 0) { red[wv * 2] = s; red[wv * 2 + 1] = sq; }
  __syncthreads();
  const float ts  = red[0] + red[2];
  const float tsq = red[1] + red[3];
  const float mean = ts * (1.0f / (float)D_);
  const float inv  = rsqrtf(tsq * (1.0f / (float)D_) - mean * mean + 1e-6f);
  const int d0 = t * 4;
  float o[4];
#pragma unroll
  for (int j = 0; j < 4; j++)
    o[j] = (va[j] - mean) * inv * sc[d0 + j] + bi[d0 + j];
  if (BF16OUT) {
    ushort4 u;
    u.x = f2b(o[0]); u.y = f2b(o[1]); u.z = f2b(o[2]); u.w = f2b(o[3]);
    ((ushort4*)outp)[(size_t)row * (D_ / 4) + t] = u;
  } else {
    ((float4*)outp)[(size_t)row * (D_ / 4) + t] = make_float4(o[0], o[1], o[2], o[3]);
  }
}

// ---------- TxT BK=64 GEMM, counted-vmcnt pipeline (T2+T3+T4+T5) ----------
// C[M,N] = A[M,K] * BT[N,K]^T. T=256: 8 waves (2Mx4N), 128KiB LDS.
//                              T=128: 4 waves (2Mx2N),  64KiB LDS.
// Per-wave output: (T/2) x 64. Slot swizzle (16B slots, 8/row): lds slot =
// gslot ^ (row&7); glds uses pre-swizzled global source + linear LDS dst.
// Loop: vmcnt(8) -> B1 -> ds_read ks0 -> MFMA ks0 -> ds_read ks1 ->
//       lgkmcnt(0) -> B2 -> stage(kt+2) -> setprio(1) MFMA ks1 setprio(0)
template <int MODE, bool VSPLIT, int T>
__global__ __launch_bounds__(T * 2)   // T=256 -> 512 thr, T=128 -> 256 thr
void gemm_pipe(const u16* __restrict__ A, const u16* __restrict__ BT,
               int Kk, int ostride,
               float* __restrict__ outf, u16* __restrict__ outb,
               const float* __restrict__ bias, const float* __restrict__ resid,
               u16* __restrict__ vtout) {
  constexpr int MI = T / 32;            // per-wave 16-row frags (8 or 4)
  constexpr int NW = T / 64;            // wave cols (4 or 2)
  __shared__ u16 As[2][T * 64];
  __shared__ u16 Bs[2][T * 64];
  const int tid = threadIdx.x;
  const int wave = tid >> 6, lane = tid & 63;
  const int row0 = blockIdx.x * T, col0 = blockIdx.y * T;
  const int wr = wave / NW, wc = wave % NW;
  const int l15 = lane & 15, l4 = lane >> 4;

  // staging sources: per wave 4 A-chunks + 4 B-chunks (64 lanes x 16B each)
  const u16* asrc[4];
  const u16* bsrc[4];
  int cdst[4];
#pragma unroll
  for (int i = 0; i < 4; i++) {
    int chunk = wave * 256 + i * 64 + lane;       // 0..T*8-1
    int r = chunk >> 3, s = chunk & 7;
    int ss = (s ^ (r & 7)) << 3;                  // pre-swizzled k-slot (u16)
    asrc[i] = A  + (size_t)(row0 + r) * Kk + ss;
    bsrc[i] = BT + (size_t)(col0 + r) * Kk + ss;
    cdst[i] = (wave * 256 + i * 64) * 8;          // wave-uniform chunk base (u16)
  }

  // frag read offsets; row&7 == l15&7 for all frags (multiples of 8 elsewhere)
  int aoff[MI], boff[4];
#pragma unroll
  for (int m = 0; m < MI; m++) aoff[m] = (wr * (MI * 16) + m * 16 + l15) * 64;
#pragma unroll
  for (int n = 0; n < 4; n++) boff[n] = (wc * 64 + n * 16 + l15) * 64;
  const int sk0 = ((l4)     ^ (l15 & 7)) << 3;    // ks=0: slot l4
  const int sk1 = ((4 + l4) ^ (l15 & 7)) << 3;    // ks=1: slot 4+l4

  f32x4 acc[MI][4] = {};
  const int nk = Kk >> 6;

  auto stage = [&](int buf, int kt) {
    const int ko = kt << 6;
#pragma unroll
    for (int i = 0; i < 4; i++) glds16(asrc[i] + ko, &As[buf][cdst[i]]);
#pragma unroll
    for (int i = 0; i < 4; i++) glds16(bsrc[i] + ko, &Bs[buf][cdst[i]]);
  };

  stage(0, 0);
  stage(1, 1);

  for (int kt = 0; kt < nk; ++kt) {
    const int cur = kt & 1;
    if (kt + 1 < nk) { asm volatile("s_waitcnt vmcnt(8)" ::: "memory"); }
    else             { asm volatile("s_waitcnt vmcnt(0)" ::: "memory"); }
    __builtin_amdgcn_s_barrier();                 // B1: buf[cur] staged everywhere
    __builtin_amdgcn_sched_barrier(0);

    bf16x8 af0[MI], bf0[4];
#pragma unroll
    for (int m = 0; m < MI; m++) af0[m] = *(const bf16x8*)&As[cur][aoff[m] + sk0];
#pragma unroll
    for (int n = 0; n < 4; n++) bf0[n] = *(const bf16x8*)&Bs[cur][boff[n] + sk0];
#pragma unroll
    for (int m = 0; m < MI; m++)
#pragma unroll
      for (int n = 0; n < 4; n++)
        acc[m][n] = __builtin_amdgcn_mfma_f32_16x16x32_bf16(af0[m], bf0[n], acc[m][n], 0, 0, 0);

    bf16x8 af1[MI], bf1[4];
#pragma unroll
    for (int m = 0; m < MI; m++) af1[m] = *(const bf16x8*)&As[cur][aoff[m] + sk1];
#pragma unroll
    for (int n = 0; n < 4; n++) bf1[n] = *(const bf16x8*)&Bs[cur][boff[n] + sk1];
    asm volatile("s_waitcnt lgkmcnt(0)" ::: "memory");
    __builtin_amdgcn_sched_barrier(0);
    __builtin_amdgcn_s_barrier();                 // B2: all reads of buf[cur] done
    __builtin_amdgcn_sched_barrier(0);
    if (kt + 2 < nk) stage(cur, kt + 2);          // overwrite buf[cur], 2 iters of flight

    __builtin_amdgcn_s_setprio(1);
#pragma unroll
    for (int m = 0; m < MI; m++)
#pragma unroll
      for (int n = 0; n < 4; n++)
        acc[m][n] = __builtin_amdgcn_mfma_f32_16x16x32_bf16(af1[m], bf1[n], acc[m][n], 0, 0, 0);
    __builtin_amdgcn_s_setprio(0);
  }

#pragma unroll
  for (int m = 0; m < MI; m++) {
#pragma unroll
    for (int n = 0; n < 4; n++) {
      const int c = col0 + wc * 64 + n * 16 + l15;
      const int rb = row0 + wr * (MI * 16) + m * 16 + l4 * 4;
      if (VSPLIT && c >= 1024) {
        u16 pk[4];
#pragma unroll
        for (int j = 0; j < 4; j++) pk[j] = f2b(acc[m][n][j]);
        *(uint2*)(vtout + (size_t)(c - 1024) * (B_ * S_) + rb) = *(const uint2*)pk;
      } else {
#pragma unroll
        for (int j = 0; j < 4; j++) {
          const size_t o = (size_t)(rb + j) * ostride + c;
          float v = acc[m][n][j];
          if (MODE == 0) {
            if (VSPLIT && c < 512) v *= QSCALE;   // pre-scale Q for base-2 softmax
            outb[o] = f2b(v);
          } else if (MODE == 1) {
            outf[o] = v + resid[o];
          } else if (MODE == 2) {
            outb[o] = f2b(gelu_f(v + bias[c]));
          } else {
            outf[o] = v + bias[c] + resid[o];
          }
        }
      }
    }
  }
}

// ---------- MFMA block-sparse attention, K/V^T double-buffered prefetch ----------
__global__ __launch_bounds__(256, 4)
void attn_mfma(const u16* __restrict__ qkv, const u16* __restrict__ vTg,
               const int* __restrict__ tokens, u16* __restrict__ outb, Plan plan) {
  __shared__ u16 ks[2][64 * 64];
  __shared__ u16 vt[2][64 * 64];
  __shared__ u16 ps[64 * 64];

  const int blk = blockIdx.x;
  const int h0 = blk & 7;
  const int n  = (blk >> 3) & 31;
  const int b  = blk >> 8;
  const int t  = threadIdx.x;
  const int wave = t >> 6, lane = t & 63;
  const int l15 = lane & 15, l4 = lane >> 4;
  const int ncnt = plan.cnt[n];
  const int qrow0 = b * S_ + n * 64;

  auto stage = [&](int bi, int c, int* tkd) {
    const int krow0 = b * S_ + c * 64;
#pragma unroll
    for (int i = 0; i < 2; i++) {
      int c0 = i * 256 + wave * 64;
      int cl = c0 + lane;
      int r = cl >> 3, s = cl & 7;
      int sw = (s ^ (r & 7)) << 3;
      glds16(qkv + (size_t)(krow0 + r) * 1024 + 512 + h0 * 64 + sw, &ks[bi][c0 * 8]);
      glds16(vTg + (size_t)(h0 * 64 + r) * (B_ * S_) + krow0 + sw, &vt[bi][c0 * 8]);
    }
#pragma unroll
    for (int nn = 0; nn < 4; nn++) tkd[nn] = tokens[krow0 + nn * 16 + l15];
  };

  bf16x8 qaf[2];
#pragma unroll
  for (int ks_ = 0; ks_ < 2; ks_++)
    qaf[ks_] = *(const bf16x8*)(qkv + (size_t)(qrow0 + wave * 16 + l15) * 1024 +
                                h0 * 64 + ks_ * 32 + l4 * 8);

  int tk[4], tn[4];
  stage(0, plan.idx[n][0], tk);

  f32x4 oacc[4] = {};
  float mrow[4], lrow[4];
#pragma unroll
  for (int j = 0; j < 4; j++) { mrow[j] = -3e38f; lrow[j] = 0.0f; }

  for (int kc = 0; kc < ncnt; kc++) {
    const int cur = kc & 1;
    __syncthreads();
    if (kc + 1 < ncnt) stage(cur ^ 1, plan.idx[n][kc + 1], tn);

    f32x4 sacc[4] = {};
#pragma unroll
    for (int nn = 0; nn < 4; nn++) {
      int r = nn * 16 + l15;
#pragma unroll
      for (int ks_ = 0; ks_ < 2; ks_++) {
        bf16x8 kf = *(const bf16x8*)(&ks[cur][r * 64 + ((ks_ * 32 + l4 * 8) ^ ((r & 7) << 3))]);
        sacc[nn] = __builtin_amdgcn_mfma_f32_16x16x32_bf16(qaf[ks_], kf, sacc[nn], 0, 0, 0);
      }
    }

    bool vld[4];
#pragma unroll
    for (int nn = 0; nn < 4; nn++) vld[nn] = tk[nn] > 0;

    float rmax[4];
#pragma unroll
    for (int j = 0; j < 4; j++) {
      float mj = -3e38f;
#pragma unroll
      for (int nn = 0; nn < 4; nn++)
        if (vld[nn]) mj = fmaxf(mj, sacc[nn][j]);
      rmax[j] = mj;
    }
#pragma unroll
    for (int d = 1; d < 16; d <<= 1) {
#pragma unroll
      for (int j = 0; j < 4; j++) rmax[j] = fmaxf(rmax[j], __shfl_xor(rmax[j], d));
    }
    int chg = 0;
#pragma unroll
    for (int j = 0; j < 4; j++) chg |= (rmax[j] > mrow[j]);
    if (__ballot(chg)) {
#pragma unroll
      for (int j = 0; j < 4; j++) {
        float mn = fmaxf(mrow[j], rmax[j]);
        float alpha = exp2f(mrow[j] - mn);
        mrow[j] = mn;
        lrow[j] *= alpha;
#pragma unroll
        for (int n2 = 0; n2 < 4; n2++) oacc[n2][j] *= alpha;
      }
    }
    float p[4][4];
#pragma unroll
    for (int j = 0; j < 4; j++) {
      float psum = 0.0f;
#pragma unroll
      for (int nn = 0; nn < 4; nn++) {
        float pv = vld[nn] ? exp2f(sacc[nn][j] - mrow[j]) : 0.0f;
        p[nn][j] = pv;
        psum += pv;
      }
      lrow[j] += psum;
    }

#pragma unroll
    for (int nn = 0; nn < 4; nn++)
#pragma unroll
      for (int j = 0; j < 4; j++) {
        int q = wave * 16 + l4 * 4 + j;
        ps[q * 64 + ((nn * 16 + l15) ^ ((q & 7) << 3))] = f2b(p[nn][j]);
      }

#pragma unroll
    for (int ks_ = 0; ks_ < 2; ks_++) {
      int r = wave * 16 + l15;
      bf16x8 paf = *(const bf16x8*)(ps + r * 64 + ((ks_ * 32 + l4 * 8) ^ ((r & 7) << 3)));
#pragma unroll
      for (int n2 = 0; n2 < 4; n2++) {
        int rv = n2 * 16 + l15;
        bf16x8 vf = *(const bf16x8*)(&vt[cur][rv * 64 + ((ks_ * 32 + l4 * 8) ^ ((rv & 7) << 3))]);
        oacc[n2] = __builtin_amdgcn_mfma_f32_16x16x32_bf16(paf, vf, oacc[n2], 0, 0, 0);
      }
    }
#pragma unroll
    for (int nn = 0; nn < 4; nn++) tk[nn] = tn[nn];
  }

#pragma unroll
  for (int d = 1; d < 16; d <<= 1) {
#pragma unroll
    for (int j = 0; j < 4; j++) lrow[j] += __shfl_xor(lrow[j], d);
  }
#pragma unroll
  for (int j = 0; j < 4; j++) {
    const float inv = lrow[j] > 0.0f ? 1.0f / lrow[j] : 0.0f;
    const int q = n * 64 + wave * 16 + l4 * 4 + j;
#pragma unroll
    for (int n2 = 0; n2 < 4; n2++) {
      outb[(size_t)(b * S_ + q) * D_ + h0 * 64 + n2 * 16 + l15] = f2b(oacc[n2][j] * inv);
    }
  }
}

// ---------- host-side exact numpy RandomState(MT19937) plan ----------
namespace {
struct HostMT {
  u32 mt[624]; int mti;
  void seed(u32 s) {
    mt[0] = s;
    for (int i = 1; i < 624; i++)
      mt[i] = 1812433253u * (mt[i - 1] ^ (mt[i - 1] >> 30)) + (u32)i;
    mti = 624;
  }
  u32 next() {
    if (mti >= 624) {
      for (int k = 0; k < 624; k++) {
        u32 y = (mt[k] & 0x80000000u) | (mt[(k + 1) % 624] & 0x7fffffffu);
        mt[k] = mt[(k + 397) % 624] ^ (y >> 1) ^ ((y & 1u) ? 0x9908b0dfu : 0u);
      }
      mti = 0;
    }
    u32 y = mt[mti++];
    y ^= y >> 11;
    y ^= (y << 7)  & 0x9d2c5680u;
    y ^= (y << 15) & 0xefc60000u;
    y ^= y >> 18;
    return y;
  }
  u32 interval(u32 mx) {
    if (mx == 0u) return 0u;
    u32 mask = mx;
    mask |= mask >> 1; mask |= mask >> 2; mask |= mask >> 4;
    mask |= mask >> 8; mask |= mask >> 16;
    u32 v;
    while ((v = (next() & mask)) > mx) {}
    return v;
  }
};

void build_plan(int l, Plan* out) {
  HostMT rng;
  rng.seed((u32)l);
  for (int i = 0; i < NB_; i++) {
    bool fixedv[NB_] = {};
    fixedv[0] = true; fixedv[NB_ - 1] = true;
    for (int j = i - 1; j <= i + 1; j++)
      if (j >= 0 && j < NB_) fixedv[j] = true;
    int rest[NB_]; int nr = 0;
    for (int j = 0; j < NB_; j++) if (!fixedv[j]) rest[nr++] = j;
    int perm[NB_];
    for (int tt = 0; tt < nr; tt++) perm[tt] = tt;
    for (int tt = nr - 1; tt >= 1; tt--) {
      int j = (int)rng.interval((u32)tt);
      int tmp = perm[tt]; perm[tt] = perm[j]; perm[j] = tmp;
    }
    bool sel[NB_];
    for (int j = 0; j < NB_; j++) sel[j] = fixedv[j];
    for (int c = 0; c < 3; c++) sel[rest[perm[c]]] = true;
    int cnt = 0;
    for (int j = 0; j < NB_; j++)
      if (sel[j]) out->idx[i][cnt++] = (unsigned char)j;
    out->cnt[i] = (unsigned char)cnt;
    for (int c2 = cnt; c2 < KC_; c2++) out->idx[i][c2] = 0;
  }
}
}  // namespace

// ---------- host orchestration ----------
extern "C" void kernel_launch(void* const* d_in, const int* in_sizes, int n_in,
                              void* d_out, int out_size, void* d_ws, size_t ws_size,
                              hipStream_t stream) {
  (void)in_sizes; (void)n_in; (void)out_size; (void)ws_size;

  const int*   tokens = (const int*)d_in[0];
  const float* embed  = (const float*)d_in[1];
  const float* ln1_s  = (const float*)d_in[2];
  const float* ln1_b  = (const float*)d_in[3];
  const float* wq     = (const float*)d_in[4];
  const float* wk     = (const float*)d_in[5];
  const float* wv     = (const float*)d_in[6];
  const float* wo     = (const float*)d_in[7];
  const float* ln2_s  = (const float*)d_in[8];
  const float* ln2_b  = (const float*)d_in[9];
  const float* w1     = (const float*)d_in[10];
  const float* b1     = (const float*)d_in[11];
  const float* w2     = (const float*)d_in[12];
  const float* b2     = (const float*)d_in[13];
  const float* lnf_s  = (const float*)d_in[14];
  const float* lnf_b  = (const float*)d_in[15];

  char* wp = (char*)d_ws;
  auto take = [&](size_t bytes) {
    void* p = (void*)wp;
    wp += (bytes + 255) & ~(size_t)255;
    return p;
  };

  const int Mrows = B_ * S_;
  u16* wqkvT = (u16*)take((size_t)L_ * 1536 * D_ * 2);   // [L][1536][512]
  u16* woT   = (u16*)take((size_t)L_ * D_ * D_ * 2);     // [L][512][512]
  u16* w1T   = (u16*)take((size_t)L_ * FF_ * D_ * 2);    // [L][2048][512]
  u16* w2T   = (u16*)take((size_t)L_ * D_ * FF_ * 2);    // [L][512][2048]
  float* x   = (float*)take((size_t)Mrows * D_ * 4);
  u16* h     = (u16*)take((size_t)Mrows * D_ * 2);
  u16* big   = (u16*)take((size_t)Mrows * FF_ * 2);      // {qkv+vT} | g, time-shared
  u16* qkv   = big;                                      // [8192][1024] q|k
  u16* vT    = big + (size_t)Mrows * 1024;               // [512][8192]
  u16* g     = big;

  Plan plans[L_];
  for (int l = 0; l < L_; l++) build_plan(l, &plans[l]);

  const size_t qkvL = (size_t)1536 * D_;

  transpose_conv<<<dim3(D_ / 32, D_ / 32, L_), dim3(32, 8), 0, stream>>>(wq, wqkvT, D_, D_, qkvL, 0);
  transpose_conv<<<dim3(D_ / 32, D_ / 32, L_), dim3(32, 8), 0, stream>>>(wk, wqkvT, D_, D_, qkvL, 512);
  transpose_conv<<<dim3(D_ / 32, D_ / 32, L_), dim3(32, 8), 0, stream>>>(wv, wqkvT, D_, D_, qkvL, 1024);
  transpose_conv<<<dim3(D_ / 32, D_ / 32, L_), dim3(32, 8), 0, stream>>>(wo, woT, D_, D_, (size_t)D_ * D_, 0);
  transpose_conv<<<dim3(FF_ / 32, D_ / 32, L_), dim3(32, 8), 0, stream>>>(w1, w1T, D_, FF_, (size_t)FF_ * D_, 0);
  transpose_conv<<<dim3(D_ / 32, FF_ / 32, L_), dim3(32, 8), 0, stream>>>(w2, w2T, FF_, D_, (size_t)D_ * FF_, 0);
  embed_kernel<<<Mrows, 128, 0, stream>>>(tokens, embed, x);

  for (int l = 0; l < L_; l++) {
    ln_kernel<true><<<Mrows, 128, 0, stream>>>(x, ln1_s + l * D_, ln1_b + l * D_, h);
    gemm_pipe<0, true, 256><<<dim3(Mrows / 256, 6), 512, 0, stream>>>(
        h, wqkvT + (size_t)l * qkvL, D_, 1024, nullptr, qkv, nullptr, nullptr, vT);
    attn_mfma<<<B_ * NB_ * H_, 256, 0, stream>>>(qkv, vT, tokens, h, plans[l]);
    gemm_pipe<1, false, 128><<<dim3(Mrows / 128, 4), 256, 0, stream>>>(
        h, woT + (size_t)l * D_ * D_, D_, D_, x, nullptr, nullptr, x, nullptr);
    ln_kernel<true><<<Mrows, 128, 0, stream>>>(x, ln2_s + l * D_, ln2_b + l * D_, h);
    gemm_pipe<2, false, 256><<<dim3(Mrows / 256, 8), 512, 0, stream>>>(
        h, w1T + (size_t)l * FF_ * D_, D_, FF_, nullptr, g, b1 + l * FF_, nullptr, nullptr);
    gemm_pipe<3, false, 128><<<dim3(Mrows / 128, 4), 256, 0, stream>>>(
        g, w2T + (size_t)l * D_ * FF_, FF_, D_, x, nullptr, b2 + l * D_, x, nullptr);
  }
  ln_kernel<false><<<Mrows, 128, 0, stream>>>(x, lnf_s, lnf_b, d_out);
}

// Round 7
// 868.840 us; speedup vs baseline: 4.5553x; 1.0108x over previous
//
#include <hip/hip_runtime.h>

using u32 = unsigned int;
using u16 = unsigned short;

#define B_   4
#define S_   2048
#define D_   512
#define H_   8
#define DH_  64
#define FF_  2048
#define L_   6
#define NB_  32
#define KC_  8

typedef __attribute__((ext_vector_type(8))) __bf16 bf16x8;
typedef __attribute__((ext_vector_type(4))) float  f32x4;

struct Plan { unsigned char idx[NB_][KC_]; unsigned char cnt[NB_]; };

// Q prescale folded into QKV GEMM epilogue: 1/sqrt(64) * log2(e)  (base-2 softmax)
#define QSCALE 0.18033688011112042f

// ---------- helpers ----------
__device__ __forceinline__ u16 f2b(float f) {
  union { __bf16 b; u16 u; } x;
  x.b = (__bf16)f;            // hw v_cvt (RNE)
  return x.u;
}

// exact tanh-gelu via sigmoid identity: 0.5*(1+tanh(y)) == 1/(1+e^{-2y})
__device__ __forceinline__ float gelu_f(float x) {
  float y2 = 1.5957691216f * x + 0.0713548163f * x * x * x;  // 2*y
  return x / (1.0f + __expf(-y2));
}

// async global->LDS 16B per lane. dst = wave-uniform base; lane l lands at +l*16B.
typedef const __attribute__((address_space(1))) u32* gas_t;
typedef __attribute__((address_space(3))) u32* las_t;
__device__ __forceinline__ void glds16(const u16* g, u16* l) {
  __builtin_amdgcn_global_load_lds((gas_t)g, (las_t)l, 16, 0, 0);
}

// ---------- weight transpose-convert: in f32 [L][R][C] -> out bf16 rows=C cols=R ----------
__global__ __launch_bounds__(256)
void transpose_conv(const float* __restrict__ in, u16* __restrict__ out, int R, int C,
                    size_t lstride, int rowoff) {
  __shared__ float tile[32][33];
  const int l = blockIdx.z;
  const float* src = in + (size_t)l * R * C;
  u16* dst = out + (size_t)l * lstride;
  const int c0 = blockIdx.x * 32, r0 = blockIdx.y * 32;
  const int tx = threadIdx.x, ty = threadIdx.y;
#pragma unroll
  for (int i = 0; i < 4; i++)
    tile[ty + i * 8][tx] = src[(size_t)(r0 + ty + i * 8) * C + c0 + tx];
  __syncthreads();
#pragma unroll
  for (int i = 0; i < 4; i++)
    dst[(size_t)(rowoff + c0 + ty + i * 8) * R + r0 + tx] = f2b(tile[tx][ty + i * 8]);
}

// ---------- embedding + sinusoidal pos ----------
__global__ __launch_bounds__(128)
void embed_kernel(const int* __restrict__ tokens, const float* __restrict__ emb,
                  float* __restrict__ x) {
  const int row = blockIdx.x;           // b*S + s
  const int s = row & (S_ - 1);
  const int t = threadIdx.x;
  const int tok = tokens[row];
  float4 v = ((const float4*)(emb + (size_t)tok * D_))[t];
  float va[4] = {v.x, v.y, v.z, v.w};
  const float cc = -2.0f * logf(10000.0f) / (float)D_;
  const float pos = (float)s;
#pragma unroll
  for (int j = 0; j < 4; j++) {
    int d = t * 4 + j;
    int i = d >> 1;
    float dv = expf(cc * (float)i);
    float ang = pos * dv;
    va[j] += (d & 1) ? cosf(ang) : sinf(ang);
  }
  ((float4*)x)[(size_t)row * (D_ / 4) + t] = make_float4(va[0], va[1], va[2], va[3]);
}

// ---------- layernorm: f32 in -> bf16 (or f32) out ----------
template <bool BF16OUT>
__global__ __launch_bounds__(128)
void ln_kernel(const float* __restrict__ x, const float* __restrict__ sc,
               const float* __restrict__ bi, void* __restrict__ outp) {
  const int row = blockIdx.x;
  const int t = threadIdx.x;
  float4 v = ((const float4*)(x + (size_t)row * D_))[t];
  float va[4] = {v.x, v.y, v.z, v.w};
  float s = va[0] + va[1] + va[2] + va[3];
  float sq = va[0] * va[0] + va[1] * va[1] + va[2] * va[2] + va[3] * va[3];
#pragma unroll
  for (int d = 1; d < 64; d <<= 1) {
    s  += __shfl_xor(s, d);
    sq += __shfl_xor(sq, d);
  }
  __shared__ float red[4];
  const int wv = t >> 6, lane = t & 63;
  if (lane == 0) { red[wv * 2] = s; red[wv * 2 + 1] = sq; }
  __syncthreads();
  const float ts  = red[0] + red[2];
  const float tsq = red[1] + red[3];
  const float mean = ts * (1.0f / (float)D_);
  const float inv  = rsqrtf(tsq * (1.0f / (float)D_) - mean * mean + 1e-6f);
  const int d0 = t * 4;
  float o[4];
#pragma unroll
  for (int j = 0; j < 4; j++)
    o[j] = (va[j] - mean) * inv * sc[d0 + j] + bi[d0 + j];
  if (BF16OUT) {
    ushort4 u;
    u.x = f2b(o[0]); u.y = f2b(o[1]); u.z = f2b(o[2]); u.w = f2b(o[3]);
    ((ushort4*)outp)[(size_t)row * (D_ / 4) + t] = u;
  } else {
    ((float4*)outp)[(size_t)row * (D_ / 4) + t] = make_float4(o[0], o[1], o[2], o[3]);
  }
}

// ---------- TMxTN BK=64 GEMM, counted-vmcnt pipeline, multi-block/CU ----------
// C[M,N] = A[M,K] * BT[N,K]^T. 256 threads (4 waves, 2x2) for TN=128.
// TM=128: LDS 64KiB -> 2 blocks/CU. TM=64: LDS 48KiB -> 3 blocks/CU.
// 1D grid with XCD swizzle (nwg%8==0): within an XCD consecutive blocks walk
// col-tiles at fixed row-tile -> activation panel stays in that XCD's L2.
// Loop: vmcnt(VM) -> B1 -> ds_read ks0 -> MFMA ks0 -> ds_read ks1 ->
//       lgkmcnt(0) -> B2 -> stage(kt+2) -> setprio(1) MFMA ks1 setprio(0)
template <int MODE, bool VSPLIT, int TM, int TN>
__global__ __launch_bounds__(TN * 2)
void gemm_pipe(const u16* __restrict__ A, const u16* __restrict__ BT,
               int Kk, int ostride, int ncols,
               float* __restrict__ outf, u16* __restrict__ outb,
               const float* __restrict__ bias, const float* __restrict__ resid,
               u16* __restrict__ vtout) {
  constexpr int NW  = TN / 32;          // waves (2x(TN/64))
  constexpr int WC  = NW / 2;           // wave cols
  constexpr int MI  = TM / 32;          // per-wave 16-row frags
  constexpr int CHA = TM / (8 * NW);    // A-stage glds per wave
  constexpr int CHB = TN / (8 * NW);    // B-stage glds per wave
  constexpr int VM  = CHA + CHB;
  __shared__ u16 As[2][TM * 64];
  __shared__ u16 Bs[2][TN * 64];
  const int tid = threadIdx.x;
  const int wave = tid >> 6, lane = tid & 63;
  const int nwg = gridDim.x, cpx = nwg >> 3;
  const int bid = blockIdx.x;
  const int gid = (bid & 7) * cpx + (bid >> 3);
  const int row0 = (gid / ncols) * TM, col0 = (gid % ncols) * TN;
  const int wr = wave / WC, wc = wave % WC;
  const int l15 = lane & 15, l4 = lane >> 4;

  // staging sources (64 lanes x 16B per chunk), pre-swizzled k-slot
  const u16* asrc[CHA];
  const u16* bsrc[CHB];
  int adst[CHA], bdst[CHB];
#pragma unroll
  for (int i = 0; i < CHA; i++) {
    int chunk = wave * (CHA * 64) + i * 64 + lane;
    int r = chunk >> 3, s = chunk & 7;
    asrc[i] = A + (size_t)(row0 + r) * Kk + ((s ^ (r & 7)) << 3);
    adst[i] = (wave * (CHA * 64) + i * 64) * 8;
  }
#pragma unroll
  for (int i = 0; i < CHB; i++) {
    int chunk = wave * (CHB * 64) + i * 64 + lane;
    int r = chunk >> 3, s = chunk & 7;
    bsrc[i] = BT + (size_t)(col0 + r) * Kk + ((s ^ (r & 7)) << 3);
    bdst[i] = (wave * (CHB * 64) + i * 64) * 8;
  }

  // frag read offsets; row&7 == l15&7 for all frags (multiples of 8 elsewhere)
  int aoff[MI], boff[4];
#pragma unroll
  for (int m = 0; m < MI; m++) aoff[m] = (wr * (MI * 16) + m * 16 + l15) * 64;
#pragma unroll
  for (int n = 0; n < 4; n++) boff[n] = (wc * 64 + n * 16 + l15) * 64;
  const int sk0 = ((l4)     ^ (l15 & 7)) << 3;    // ks=0: slot l4
  const int sk1 = ((4 + l4) ^ (l15 & 7)) << 3;    // ks=1: slot 4+l4

  f32x4 acc[MI][4] = {};
  const int nk = Kk >> 6;

  auto stage = [&](int buf, int kt) {
    const int ko = kt << 6;
#pragma unroll
    for (int i = 0; i < CHA; i++) glds16(asrc[i] + ko, &As[buf][adst[i]]);
#pragma unroll
    for (int i = 0; i < CHB; i++) glds16(bsrc[i] + ko, &Bs[buf][bdst[i]]);
  };

  stage(0, 0);
  stage(1, 1);

  for (int kt = 0; kt < nk; ++kt) {
    const int cur = kt & 1;
    if (kt + 1 < nk) {
      if constexpr (VM == 8) { asm volatile("s_waitcnt vmcnt(8)" ::: "memory"); }
      else                   { asm volatile("s_waitcnt vmcnt(6)" ::: "memory"); }
    } else {
      asm volatile("s_waitcnt vmcnt(0)" ::: "memory");
    }
    __builtin_amdgcn_s_barrier();                 // B1: buf[cur] staged everywhere
    __builtin_amdgcn_sched_barrier(0);

    bf16x8 af0[MI], bf0[4];
#pragma unroll
    for (int m = 0; m < MI; m++) af0[m] = *(const bf16x8*)&As[cur][aoff[m] + sk0];
#pragma unroll
    for (int n = 0; n < 4; n++) bf0[n] = *(const bf16x8*)&Bs[cur][boff[n] + sk0];
#pragma unroll
    for (int m = 0; m < MI; m++)
#pragma unroll
      for (int n = 0; n < 4; n++)
        acc[m][n] = __builtin_amdgcn_mfma_f32_16x16x32_bf16(af0[m], bf0[n], acc[m][n], 0, 0, 0);

    bf16x8 af1[MI], bf1[4];
#pragma unroll
    for (int m = 0; m < MI; m++) af1[m] = *(const bf16x8*)&As[cur][aoff[m] + sk1];
#pragma unroll
    for (int n = 0; n < 4; n++) bf1[n] = *(const bf16x8*)&Bs[cur][boff[n] + sk1];
    asm volatile("s_waitcnt lgkmcnt(0)" ::: "memory");
    __builtin_amdgcn_sched_barrier(0);
    __builtin_amdgcn_s_barrier();                 // B2: all reads of buf[cur] done
    __builtin_amdgcn_sched_barrier(0);
    if (kt + 2 < nk) stage(cur, kt + 2);          // overwrite buf[cur], 2 iters of flight

    __builtin_amdgcn_s_setprio(1);
#pragma unroll
    for (int m = 0; m < MI; m++)
#pragma unroll
      for (int n = 0; n < 4; n++)
        acc[m][n] = __builtin_amdgcn_mfma_f32_16x16x32_bf16(af1[m], bf1[n], acc[m][n], 0, 0, 0);
    __builtin_amdgcn_s_setprio(0);
  }

#pragma unroll
  for (int m = 0; m < MI; m++) {
#pragma unroll
    for (int n = 0; n < 4; n++) {
      const int c = col0 + wc * 64 + n * 16 + l15;
      const int rb = row0 + wr * (MI * 16) + m * 16 + l4 * 4;
      if (VSPLIT && c >= 1024) {
        u16 pk[4];
#pragma unroll
        for (int j = 0; j < 4; j++) pk[j] = f2b(acc[m][n][j]);
        *(uint2*)(vtout + (size_t)(c - 1024) * (B_ * S_) + rb) = *(const uint2*)pk;
      } else {
#pragma unroll
        for (int j = 0; j < 4; j++) {
          const size_t o = (size_t)(rb + j) * ostride + c;
          float v = acc[m][n][j];
          if (MODE == 0) {
            if (VSPLIT && c < 512) v *= QSCALE;   // pre-scale Q for base-2 softmax
            outb[o] = f2b(v);
          } else if (MODE == 1) {
            outf[o] = v + resid[o];
          } else if (MODE == 2) {
            outb[o] = f2b(gelu_f(v + bias[c]));
          } else {
            outf[o] = v + bias[c] + resid[o];
          }
        }
      }
    }
  }
}

// ---------- MFMA block-sparse attention, K/V^T double-buffered prefetch ----------
__global__ __launch_bounds__(256, 4)
void attn_mfma(const u16* __restrict__ qkv, const u16* __restrict__ vTg,
               const int* __restrict__ tokens, u16* __restrict__ outb, Plan plan) {
  __shared__ u16 ks[2][64 * 64];
  __shared__ u16 vt[2][64 * 64];
  __shared__ u16 ps[64 * 64];

  const int blk = blockIdx.x;
  const int h0 = blk & 7;
  const int n  = (blk >> 3) & 31;
  const int b  = blk >> 8;
  const int t  = threadIdx.x;
  const int wave = t >> 6, lane = t & 63;
  const int l15 = lane & 15, l4 = lane >> 4;
  const int ncnt = plan.cnt[n];
  const int qrow0 = b * S_ + n * 64;

  auto stage = [&](int bi, int c, int* tkd) {
    const int krow0 = b * S_ + c * 64;
#pragma unroll
    for (int i = 0; i < 2; i++) {
      int c0 = i * 256 + wave * 64;
      int cl = c0 + lane;
      int r = cl >> 3, s = cl & 7;
      int sw = (s ^ (r & 7)) << 3;
      glds16(qkv + (size_t)(krow0 + r) * 1024 + 512 + h0 * 64 + sw, &ks[bi][c0 * 8]);
      glds16(vTg + (size_t)(h0 * 64 + r) * (B_ * S_) + krow0 + sw, &vt[bi][c0 * 8]);
    }
#pragma unroll
    for (int nn = 0; nn < 4; nn++) tkd[nn] = tokens[krow0 + nn * 16 + l15];
  };

  bf16x8 qaf[2];
#pragma unroll
  for (int ks_ = 0; ks_ < 2; ks_++)
    qaf[ks_] = *(const bf16x8*)(qkv + (size_t)(qrow0 + wave * 16 + l15) * 1024 +
                                h0 * 64 + ks_ * 32 + l4 * 8);

  int tk[4], tn[4];
  stage(0, plan.idx[n][0], tk);

  f32x4 oacc[4] = {};
  float mrow[4], lrow[4];
#pragma unroll
  for (int j = 0; j < 4; j++) { mrow[j] = -3e38f; lrow[j] = 0.0f; }

  for (int kc = 0; kc < ncnt; kc++) {
    const int cur = kc & 1;
    __syncthreads();
    if (kc + 1 < ncnt) stage(cur ^ 1, plan.idx[n][kc + 1], tn);

    f32x4 sacc[4] = {};
#pragma unroll
    for (int nn = 0; nn < 4; nn++) {
      int r = nn * 16 + l15;
#pragma unroll
      for (int ks_ = 0; ks_ < 2; ks_++) {
        bf16x8 kf = *(const bf16x8*)(&ks[cur][r * 64 + ((ks_ * 32 + l4 * 8) ^ ((r & 7) << 3))]);
        sacc[nn] = __builtin_amdgcn_mfma_f32_16x16x32_bf16(qaf[ks_], kf, sacc[nn], 0, 0, 0);
      }
    }

    bool vld[4];
#pragma unroll
    for (int nn = 0; nn < 4; nn++) vld[nn] = tk[nn] > 0;

    float rmax[4];
#pragma unroll
    for (int j = 0; j < 4; j++) {
      float mj = -3e38f;
#pragma unroll
      for (int nn = 0; nn < 4; nn++)
        if (vld[nn]) mj = fmaxf(mj, sacc[nn][j]);
      rmax[j] = mj;
    }
#pragma unroll
    for (int d = 1; d < 16; d <<= 1) {
#pragma unroll
      for (int j = 0; j < 4; j++) rmax[j] = fmaxf(rmax[j], __shfl_xor(rmax[j], d));
    }
    int chg = 0;
#pragma unroll
    for (int j = 0; j < 4; j++) chg |= (rmax[j] > mrow[j]);
    if (__ballot(chg)) {
#pragma unroll
      for (int j = 0; j < 4; j++) {
        float mn = fmaxf(mrow[j], rmax[j]);
        float alpha = exp2f(mrow[j] - mn);
        mrow[j] = mn;
        lrow[j] *= alpha;
#pragma unroll
        for (int n2 = 0; n2 < 4; n2++) oacc[n2][j] *= alpha;
      }
    }
    float p[4][4];
#pragma unroll
    for (int j = 0; j < 4; j++) {
      float psum = 0.0f;
#pragma unroll
      for (int nn = 0; nn < 4; nn++) {
        float pv = vld[nn] ? exp2f(sacc[nn][j] - mrow[j]) : 0.0f;
        p[nn][j] = pv;
        psum += pv;
      }
      lrow[j] += psum;
    }

#pragma unroll
    for (int nn = 0; nn < 4; nn++)
#pragma unroll
      for (int j = 0; j < 4; j++) {
        int q = wave * 16 + l4 * 4 + j;
        ps[q * 64 + ((nn * 16 + l15) ^ ((q & 7) << 3))] = f2b(p[nn][j]);
      }

#pragma unroll
    for (int ks_ = 0; ks_ < 2; ks_++) {
      int r = wave * 16 + l15;
      bf16x8 paf = *(const bf16x8*)(ps + r * 64 + ((ks_ * 32 + l4 * 8) ^ ((r & 7) << 3)));
#pragma unroll
      for (int n2 = 0; n2 < 4; n2++) {
        int rv = n2 * 16 + l15;
        bf16x8 vf = *(const bf16x8*)(&vt[cur][rv * 64 + ((ks_ * 32 + l4 * 8) ^ ((rv & 7) << 3))]);
        oacc[n2] = __builtin_amdgcn_mfma_f32_16x16x32_bf16(paf, vf, oacc[n2], 0, 0, 0);
      }
    }
#pragma unroll
    for (int nn = 0; nn < 4; nn++) tk[nn] = tn[nn];
  }

#pragma unroll
  for (int d = 1; d < 16; d <<= 1) {
#pragma unroll
    for (int j = 0; j < 4; j++) lrow[j] += __shfl_xor(lrow[j], d);
  }
#pragma unroll
  for (int j = 0; j < 4; j++) {
    const float inv = lrow[j] > 0.0f ? 1.0f / lrow[j] : 0.0f;
    const int q = n * 64 + wave * 16 + l4 * 4 + j;
#pragma unroll
    for (int n2 = 0; n2 < 4; n2++) {
      outb[(size_t)(b * S_ + q) * D_ + h0 * 64 + n2 * 16 + l15] = f2b(oacc[n2][j] * inv);
    }
  }
}

// ---------- host-side exact numpy RandomState(MT19937) plan ----------
namespace {
struct HostMT {
  u32 mt[624]; int mti;
  void seed(u32 s) {
    mt[0] = s;
    for (int i = 1; i < 624; i++)
      mt[i] = 1812433253u * (mt[i - 1] ^ (mt[i - 1] >> 30)) + (u32)i;
    mti = 624;
  }
  u32 next() {
    if (mti >= 624) {
      for (int k = 0; k < 624; k++) {
        u32 y = (mt[k] & 0x80000000u) | (mt[(k + 1) % 624] & 0x7fffffffu);
        mt[k] = mt[(k + 397) % 624] ^ (y >> 1) ^ ((y & 1u) ? 0x9908b0dfu : 0u);
      }
      mti = 0;
    }
    u32 y = mt[mti++];
    y ^= y >> 11;
    y ^= (y << 7)  & 0x9d2c5680u;
    y ^= (y << 15) & 0xefc60000u;
    y ^= y >> 18;
    return y;
  }
  u32 interval(u32 mx) {
    if (mx == 0u) return 0u;
    u32 mask = mx;
    mask |= mask >> 1; mask |= mask >> 2; mask |= mask >> 4;
    mask |= mask >> 8; mask |= mask >> 16;
    u32 v;
    while ((v = (next() & mask)) > mx) {}
    return v;
  }
};

void build_plan(int l, Plan* out) {
  HostMT rng;
  rng.seed((u32)l);
  for (int i = 0; i < NB_; i++) {
    bool fixedv[NB_] = {};
    fixedv[0] = true; fixedv[NB_ - 1] = true;
    for (int j = i - 1; j <= i + 1; j++)
      if (j >= 0 && j < NB_) fixedv[j] = true;
    int rest[NB_]; int nr = 0;
    for (int j = 0; j < NB_; j++) if (!fixedv[j]) rest[nr++] = j;
    int perm[NB_];
    for (int tt = 0; tt < nr; tt++) perm[tt] = tt;
    for (int tt = nr - 1; tt >= 1; tt--) {
      int j = (int)rng.interval((u32)tt);
      int tmp = perm[tt]; perm[tt] = perm[j]; perm[j] = tmp;
    }
    bool sel[NB_];
    for (int j = 0; j < NB_; j++) sel[j] = fixedv[j];
    for (int c = 0; c < 3; c++) sel[rest[perm[c]]] = true;
    int cnt = 0;
    for (int j = 0; j < NB_; j++)
      if (sel[j]) out->idx[i][cnt++] = (unsigned char)j;
    out->cnt[i] = (unsigned char)cnt;
    for (int c2 = cnt; c2 < KC_; c2++) out->idx[i][c2] = 0;
  }
}
}  // namespace

// ---------- host orchestration ----------
extern "C" void kernel_launch(void* const* d_in, const int* in_sizes, int n_in,
                              void* d_out, int out_size, void* d_ws, size_t ws_size,
                              hipStream_t stream) {
  (void)in_sizes; (void)n_in; (void)out_size; (void)ws_size;

  const int*   tokens = (const int*)d_in[0];
  const float* embed  = (const float*)d_in[1];
  const float* ln1_s  = (const float*)d_in[2];
  const float* ln1_b  = (const float*)d_in[3];
  const float* wq     = (const float*)d_in[4];
  const float* wk     = (const float*)d_in[5];
  const float* wv     = (const float*)d_in[6];
  const float* wo     = (const float*)d_in[7];
  const float* ln2_s  = (const float*)d_in[8];
  const float* ln2_b  = (const float*)d_in[9];
  const float* w1     = (const float*)d_in[10];
  const float* b1     = (const float*)d_in[11];
  const float* w2     = (const float*)d_in[12];
  const float* b2     = (const float*)d_in[13];
  const float* lnf_s  = (const float*)d_in[14];
  const float* lnf_b  = (const float*)d_in[15];

  char* wp = (char*)d_ws;
  auto take = [&](size_t bytes) {
    void* p = (void*)wp;
    wp += (bytes + 255) & ~(size_t)255;
    return p;
  };

  const int Mrows = B_ * S_;
  u16* wqkvT = (u16*)take((size_t)L_ * 1536 * D_ * 2);   // [L][1536][512]
  u16* woT   = (u16*)take((size_t)L_ * D_ * D_ * 2);     // [L][512][512]
  u16* w1T   = (u16*)take((size_t)L_ * FF_ * D_ * 2);    // [L][2048][512]
  u16* w2T   = (u16*)take((size_t)L_ * D_ * FF_ * 2);    // [L][512][2048]
  float* x   = (float*)take((size_t)Mrows * D_ * 4);
  u16* h     = (u16*)take((size_t)Mrows * D_ * 2);
  u16* big   = (u16*)take((size_t)Mrows * FF_ * 2);      // {qkv+vT} | g, time-shared
  u16* qkv   = big;                                      // [8192][1024] q|k
  u16* vT    = big + (size_t)Mrows * 1024;               // [512][8192]
  u16* g     = big;

  Plan plans[L_];
  for (int l = 0; l < L_; l++) build_plan(l, &plans[l]);

  const size_t qkvL = (size_t)1536 * D_;

  transpose_conv<<<dim3(D_ / 32, D_ / 32, L_), dim3(32, 8), 0, stream>>>(wq, wqkvT, D_, D_, qkvL, 0);
  transpose_conv<<<dim3(D_ / 32, D_ / 32, L_), dim3(32, 8), 0, stream>>>(wk, wqkvT, D_, D_, qkvL, 512);
  transpose_conv<<<dim3(D_ / 32, D_ / 32, L_), dim3(32, 8), 0, stream>>>(wv, wqkvT, D_, D_, qkvL, 1024);
  transpose_conv<<<dim3(D_ / 32, D_ / 32, L_), dim3(32, 8), 0, stream>>>(wo, woT, D_, D_, (size_t)D_ * D_, 0);
  transpose_conv<<<dim3(FF_ / 32, D_ / 32, L_), dim3(32, 8), 0, stream>>>(w1, w1T, D_, FF_, (size_t)FF_ * D_, 0);
  transpose_conv<<<dim3(D_ / 32, FF_ / 32, L_), dim3(32, 8), 0, stream>>>(w2, w2T, FF_, D_, (size_t)D_ * FF_, 0);
  embed_kernel<<<Mrows, 128, 0, stream>>>(tokens, embed, x);

  for (int l = 0; l < L_; l++) {
    ln_kernel<true><<<Mrows, 128, 0, stream>>>(x, ln1_s + l * D_, ln1_b + l * D_, h);
    gemm_pipe<0, true, 128, 128><<<768, 256, 0, stream>>>(
        h, wqkvT + (size_t)l * qkvL, D_, 1024, 12, nullptr, qkv, nullptr, nullptr, vT);
    attn_mfma<<<B_ * NB_ * H_, 256, 0, stream>>>(qkv, vT, tokens, h, plans[l]);
    gemm_pipe<1, false, 64, 128><<<512, 256, 0, stream>>>(
        h, woT + (size_t)l * D_ * D_, D_, D_, 4, x, nullptr, nullptr, x, nullptr);
    ln_kernel<true><<<Mrows, 128, 0, stream>>>(x, ln2_s + l * D_, ln2_b + l * D_, h);
    gemm_pipe<2, false, 128, 128><<<1024, 256, 0, stream>>>(
        h, w1T + (size_t)l * FF_ * D_, D_, FF_, 16, nullptr, g, b1 + l * FF_, nullptr, nullptr);
    gemm_pipe<3, false, 64, 128><<<512, 256, 0, stream>>>(
        g, w2T + (size_t)l * D_ * FF_, FF_, D_, 4, x, nullptr, b2 + l * D_, x, nullptr);
  }
  ln_kernel<false><<<Mrows, 128, 0, stream>>>(x, lnf_s, lnf_b, d_out);
}